// Round 1
// baseline (4047.292 us; speedup 1.0000x reference)
//
#include <hip/hip_runtime.h>
#include <math.h>

#define TKN 2048
#define DIM 1024
#define NHEAD 16
#define HDIM 64
#define HFF 2048
#define NE 8
#define TOPK 2
#define NCLS 10
#define NLAYER 4
#define SEQ 256
#define BATCH 8

#define BM 64
#define BN 64
#define BKK 16

// ---------------- embed + positional encoding ----------------
// x[b,s,d] = emb[src[b,s],d]*sqrt(D) + pe(b,d)   (pe indexed by BATCH per reference quirk)
__global__ __launch_bounds__(256) void k_embed(const int* __restrict__ src,
                                               const float* __restrict__ emb,
                                               float* __restrict__ x) {
  const int t = blockIdx.x;
  const int tid = threadIdx.x;
  const int b = t / SEQ;
  const int tok = src[t];
  const float* erow = emb + (size_t)tok * DIM;
  float* xrow = x + (size_t)t * DIM;
  const float cexp = -9.210340371976184f / 1024.0f;  // -ln(10000)/D
#pragma unroll
  for (int j = 0; j < 4; ++j) {
    int d = tid + 256 * j;
    int i2 = d & ~1;
    float ang = (float)b * expf((float)i2 * cexp);
    float pe = (d & 1) ? cosf(ang) : sinf(ang);
    xrow[d] = erow[d] * 32.0f + pe;
  }
}

// ---------------- C[M,N] = A[M,K] * W[N,K]^T + bias ----------------
__global__ __launch_bounds__(256) void k_gemm_bt(const float* __restrict__ A,
                                                 const float* __restrict__ W,
                                                 const float* __restrict__ bias,
                                                 float* __restrict__ C,
                                                 int M, int N, int Kd) {
  __shared__ float As[BKK][BM + 4];
  __shared__ float Bs[BKK][BN + 4];
  const int tid = threadIdx.x;
  const int bm = blockIdx.y * BM, bn = blockIdx.x * BN;
  const int tx = tid & 15, ty = tid >> 4;
  const int srow = tid >> 2, skq = (tid & 3) << 2;
  const float* Ap = A + (size_t)(bm + srow) * Kd + skq;
  const float* Wp = W + (size_t)(bn + srow) * Kd + skq;
  float acc[4][4] = {};
  for (int k0 = 0; k0 < Kd; k0 += BKK) {
    float4 av = *(const float4*)(Ap + k0);
    float4 bv = *(const float4*)(Wp + k0);
    As[skq + 0][srow] = av.x; As[skq + 1][srow] = av.y;
    As[skq + 2][srow] = av.z; As[skq + 3][srow] = av.w;
    Bs[skq + 0][srow] = bv.x; Bs[skq + 1][srow] = bv.y;
    Bs[skq + 2][srow] = bv.z; Bs[skq + 3][srow] = bv.w;
    __syncthreads();
#pragma unroll
    for (int kk = 0; kk < BKK; ++kk) {
      float4 a = *(const float4*)&As[kk][ty << 2];
      float4 b = *(const float4*)&Bs[kk][tx << 2];
      acc[0][0] += a.x * b.x; acc[0][1] += a.x * b.y; acc[0][2] += a.x * b.z; acc[0][3] += a.x * b.w;
      acc[1][0] += a.y * b.x; acc[1][1] += a.y * b.y; acc[1][2] += a.y * b.z; acc[1][3] += a.y * b.w;
      acc[2][0] += a.z * b.x; acc[2][1] += a.z * b.y; acc[2][2] += a.z * b.z; acc[2][3] += a.z * b.w;
      acc[3][0] += a.w * b.x; acc[3][1] += a.w * b.y; acc[3][2] += a.w * b.z; acc[3][3] += a.w * b.w;
    }
    __syncthreads();
  }
  const float4 bb = *(const float4*)(bias + bn + (tx << 2));
#pragma unroll
  for (int r = 0; r < 4; ++r) {
    float4 o;
    o.x = acc[r][0] + bb.x; o.y = acc[r][1] + bb.y;
    o.z = acc[r][2] + bb.z; o.w = acc[r][3] + bb.w;
    *(float4*)(C + (size_t)(bm + (ty << 2) + r) * N + bn + (tx << 2)) = o;
  }
}

// ---------------- attention: 16 q-rows per block ----------------
__global__ __launch_bounds__(256) void k_attn(const float* __restrict__ qkv,
                                              float* __restrict__ o) {
  const int qt = blockIdx.x;
  const int hh = blockIdx.y;
  const int bb = blockIdx.z;
  const int tid = threadIdx.x;
  __shared__ float qs[16][64];
  __shared__ float ps[16][256];
  const int t0 = bb * SEQ + qt * 16;
  for (int i = tid; i < 16 * 64; i += 256) {
    int qi = i >> 6, d = i & 63;
    qs[qi][d] = qkv[(size_t)(t0 + qi) * (3 * DIM) + hh * 64 + d];
  }
  __syncthreads();
  // scores: thread handles key index `tid`
  float s[16];
#pragma unroll
  for (int qi = 0; qi < 16; ++qi) s[qi] = 0.f;
  const float* krow = qkv + (size_t)(bb * SEQ + tid) * (3 * DIM) + DIM + hh * 64;
#pragma unroll 4
  for (int c = 0; c < 16; ++c) {
    float4 kv = *(const float4*)(krow + c * 4);
#pragma unroll
    for (int qi = 0; qi < 16; ++qi) {
      s[qi] += kv.x * qs[qi][c * 4 + 0] + kv.y * qs[qi][c * 4 + 1] +
               kv.z * qs[qi][c * 4 + 2] + kv.w * qs[qi][c * 4 + 3];
    }
  }
#pragma unroll
  for (int qi = 0; qi < 16; ++qi) ps[qi][tid] = s[qi] * 0.125f;  // 1/sqrt(64)
  __syncthreads();
  const int wv = tid >> 6, lane = tid & 63;
  for (int rr = wv; rr < 16; rr += 4) {
    float v[4];
#pragma unroll
    for (int j = 0; j < 4; ++j) v[j] = ps[rr][lane + 64 * j];
    float m = fmaxf(fmaxf(v[0], v[1]), fmaxf(v[2], v[3]));
    for (int msk = 32; msk; msk >>= 1) m = fmaxf(m, __shfl_xor(m, msk));
    float e[4], sum = 0.f;
#pragma unroll
    for (int j = 0; j < 4; ++j) { e[j] = expf(v[j] - m); sum += e[j]; }
    for (int msk = 32; msk; msk >>= 1) sum += __shfl_xor(sum, msk);
    float inv = 1.0f / sum;
#pragma unroll
    for (int j = 0; j < 4; ++j) ps[rr][lane + 64 * j] = e[j] * inv;
  }
  __syncthreads();
  const int qi0 = tid >> 6, d = tid & 63;
  float acc[4] = {0.f, 0.f, 0.f, 0.f};
  const float* vbase = qkv + (size_t)(bb * SEQ) * (3 * DIM) + 2 * DIM + hh * 64 + d;
  for (int k = 0; k < 256; ++k) {
    float vv = vbase[(size_t)k * (3 * DIM)];
    acc[0] += ps[qi0][k] * vv;
    acc[1] += ps[qi0 + 4][k] * vv;
    acc[2] += ps[qi0 + 8][k] * vv;
    acc[3] += ps[qi0 + 12][k] * vv;
  }
#pragma unroll
  for (int j = 0; j < 4; ++j)
    o[(size_t)(t0 + qi0 + 4 * j) * DIM + hh * 64 + d] = acc[j];
}

// ---------------- block reduce helper ----------------
__device__ __forceinline__ float block_reduce_sum(float v, float* red) {
  const int tid = threadIdx.x;
  red[tid] = v;
  __syncthreads();
  for (int s = 128; s > 0; s >>= 1) {
    if (tid < s) red[tid] += red[tid + s];
    __syncthreads();
  }
  float r = red[0];
  __syncthreads();
  return r;
}

// ---------------- x = LN(xin + add) ----------------
__global__ __launch_bounds__(256) void k_add_ln(const float* __restrict__ xin,
                                                const float* __restrict__ add,
                                                const float* __restrict__ g,
                                                const float* __restrict__ bt,
                                                float* __restrict__ xout) {
  __shared__ float red[256];
  const int t = blockIdx.x, tid = threadIdx.x;
  const size_t base = (size_t)t * DIM;
  float v[4];
  float s = 0.f;
#pragma unroll
  for (int j = 0; j < 4; ++j) {
    int d = tid + 256 * j;
    v[j] = xin[base + d] + add[base + d];
    s += v[j];
  }
  float mean = block_reduce_sum(s, red) * (1.0f / DIM);
  float s2 = 0.f;
#pragma unroll
  for (int j = 0; j < 4; ++j) { float dv = v[j] - mean; s2 += dv * dv; }
  float var = block_reduce_sum(s2, red) * (1.0f / DIM);
  float rs = rsqrtf(var + 1e-5f);
#pragma unroll
  for (int j = 0; j < 4; ++j) {
    int d = tid + 256 * j;
    xout[base + d] = (v[j] - mean) * rs * g[d] + bt[d];
  }
}

// ---------------- gate: logits (to d_out), top-2 + softmax weights ----------------
__global__ __launch_bounds__(256) void k_gate(const float* __restrict__ x,
                                              const float* __restrict__ gw,
                                              const float* __restrict__ gb,
                                              float* __restrict__ gout,
                                              int* __restrict__ topi,
                                              float* __restrict__ topw) {
  __shared__ float xs[DIM];
  __shared__ float lgs[NE];
  const int t = blockIdx.x, tid = threadIdx.x;
#pragma unroll
  for (int j = 0; j < 4; ++j) xs[tid + 256 * j] = x[(size_t)t * DIM + tid + 256 * j];
  __syncthreads();
  const int eg = tid >> 5, l32 = tid & 31;
  const float* wrow = gw + (size_t)eg * DIM;
  float p = 0.f;
  for (int j = 0; j < 32; ++j) {
    int d = l32 + 32 * j;
    p += xs[d] * wrow[d];
  }
  for (int m = 16; m; m >>= 1) p += __shfl_xor(p, m);
  if (l32 == 0) lgs[eg] = p;
  __syncthreads();
  if (tid < NE) {
    float v = lgs[tid] + gb[tid];
    gout[(size_t)t * NE + tid] = v;
    lgs[tid] = v;
  }
  __syncthreads();
  if (tid == 0) {
    int i0 = 0; float v0 = lgs[0];
    for (int i = 1; i < NE; ++i) if (lgs[i] > v0) { v0 = lgs[i]; i0 = i; }
    int i1 = -1; float v1 = -1e30f;
    for (int i = 0; i < NE; ++i) { if (i == i0) continue; if (lgs[i] > v1) { v1 = lgs[i]; i1 = i; } }
    float e1 = expf(v1 - v0);
    float w0 = 1.0f / (1.0f + e1);
    topi[2 * t] = i0; topi[2 * t + 1] = i1;
    topw[2 * t] = w0; topw[2 * t + 1] = e1 * w0;
  }
}

// ---------------- deterministic routing build (8 waves, one per expert) ----------------
__global__ __launch_bounds__(512) void k_route(const int* __restrict__ topi,
                                               int* __restrict__ offg,
                                               int* __restrict__ slot_token,
                                               int* __restrict__ slot_of) {
  __shared__ int cnt_s[NE];
  __shared__ int off_s[NE + 1];
  const int tid = threadIdx.x;
  const int w = tid >> 6, lane = tid & 63;
  int c = 0;
  for (int i = lane; i < TKN * TOPK; i += 64) c += (topi[i] == w) ? 1 : 0;
  for (int m = 32; m; m >>= 1) c += __shfl_xor(c, m);
  if (lane == 0) cnt_s[w] = c;
  __syncthreads();
  if (tid == 0) {
    off_s[0] = 0;
    for (int e2 = 0; e2 < NE; ++e2) off_s[e2 + 1] = off_s[e2] + cnt_s[e2];
    for (int e2 = 0; e2 <= NE; ++e2) offg[e2] = off_s[e2];
  }
  __syncthreads();
  int base = off_s[w];
  for (int i0 = 0; i0 < TKN * TOPK; i0 += 64) {
    int i = i0 + lane;
    bool mm = (topi[i] == w);
    unsigned long long mask = __ballot(mm ? 1 : 0);
    int rank = __popcll(mask & ((1ull << lane) - 1ull));
    if (mm) {
      int slot = base + rank;
      slot_token[slot] = i >> 1;
      slot_of[i] = slot;
    }
    base += __popcll(mask);
  }
}

// ---------------- expert GEMM1: h[slot] = relu(x[token] @ w1[e] + b1[e]) ----------------
__global__ __launch_bounds__(256) void k_moe_gemm1(const float* __restrict__ x,
                                                   const float* __restrict__ w1,
                                                   const float* __restrict__ b1,
                                                   const int* __restrict__ slot_token,
                                                   const int* __restrict__ offg,
                                                   float* __restrict__ h) {
  const int eg = blockIdx.z;
  const int r0 = offg[eg], rows = offg[eg + 1] - r0;
  const int m0 = blockIdx.y * BM;
  if (m0 >= rows) return;
  __shared__ float As[BKK][BM + 4];
  __shared__ float Bs[BKK][BN + 4];
  __shared__ int toks[BM];
  const int tid = threadIdx.x;
  const int bn = blockIdx.x * BN;
  if (tid < BM) {
    int rr = m0 + tid;
    toks[tid] = slot_token[r0 + (rr < rows ? rr : 0)];
  }
  __syncthreads();
  const int tx = tid & 15, ty = tid >> 4;
  const int srow = tid >> 2, skq = (tid & 3) << 2;
  const int bk = tid >> 4, bn4 = (tid & 15) << 2;
  const float* W = w1 + (size_t)eg * DIM * HFF;
  const float* Ap = x + (size_t)toks[srow] * DIM + skq;
  float acc[4][4] = {};
  for (int k0 = 0; k0 < DIM; k0 += BKK) {
    float4 av = *(const float4*)(Ap + k0);
    float4 bv = *(const float4*)(W + (size_t)(k0 + bk) * HFF + bn + bn4);
    As[skq + 0][srow] = av.x; As[skq + 1][srow] = av.y;
    As[skq + 2][srow] = av.z; As[skq + 3][srow] = av.w;
    *(float4*)&Bs[bk][bn4] = bv;
    __syncthreads();
#pragma unroll
    for (int kk = 0; kk < BKK; ++kk) {
      float4 a = *(const float4*)&As[kk][ty << 2];
      float4 b = *(const float4*)&Bs[kk][tx << 2];
      acc[0][0] += a.x * b.x; acc[0][1] += a.x * b.y; acc[0][2] += a.x * b.z; acc[0][3] += a.x * b.w;
      acc[1][0] += a.y * b.x; acc[1][1] += a.y * b.y; acc[1][2] += a.y * b.z; acc[1][3] += a.y * b.w;
      acc[2][0] += a.z * b.x; acc[2][1] += a.z * b.y; acc[2][2] += a.z * b.z; acc[2][3] += a.z * b.w;
      acc[3][0] += a.w * b.x; acc[3][1] += a.w * b.y; acc[3][2] += a.w * b.z; acc[3][3] += a.w * b.w;
    }
    __syncthreads();
  }
  const float* b1e = b1 + (size_t)eg * HFF;
  const float4 bb = *(const float4*)(b1e + bn + (tx << 2));
#pragma unroll
  for (int r = 0; r < 4; ++r) {
    int rr = m0 + (ty << 2) + r;
    if (rr < rows) {
      float4 o;
      o.x = fmaxf(acc[r][0] + bb.x, 0.f); o.y = fmaxf(acc[r][1] + bb.y, 0.f);
      o.z = fmaxf(acc[r][2] + bb.z, 0.f); o.w = fmaxf(acc[r][3] + bb.w, 0.f);
      *(float4*)(h + (size_t)(r0 + rr) * HFF + bn + (tx << 2)) = o;
    }
  }
}

// ---------------- expert GEMM2: y[slot] = h[slot] @ w2[e] + b2[e] ----------------
__global__ __launch_bounds__(256) void k_moe_gemm2(const float* __restrict__ h,
                                                   const float* __restrict__ w2,
                                                   const float* __restrict__ b2,
                                                   const int* __restrict__ offg,
                                                   float* __restrict__ y) {
  const int eg = blockIdx.z;
  const int r0 = offg[eg], rows = offg[eg + 1] - r0;
  const int m0 = blockIdx.y * BM;
  if (m0 >= rows) return;
  __shared__ float As[BKK][BM + 4];
  __shared__ float Bs[BKK][BN + 4];
  const int tid = threadIdx.x;
  const int bn = blockIdx.x * BN;
  const int tx = tid & 15, ty = tid >> 4;
  const int srow = tid >> 2, skq = (tid & 3) << 2;
  const int bk = tid >> 4, bn4 = (tid & 15) << 2;
  const float* W = w2 + (size_t)eg * HFF * DIM;
  int arow = m0 + srow; if (arow >= rows) arow = 0;
  const float* Ap = h + (size_t)(r0 + arow) * HFF + skq;
  float acc[4][4] = {};
  for (int k0 = 0; k0 < HFF; k0 += BKK) {
    float4 av = *(const float4*)(Ap + k0);
    float4 bv = *(const float4*)(W + (size_t)(k0 + bk) * DIM + bn + bn4);
    As[skq + 0][srow] = av.x; As[skq + 1][srow] = av.y;
    As[skq + 2][srow] = av.z; As[skq + 3][srow] = av.w;
    *(float4*)&Bs[bk][bn4] = bv;
    __syncthreads();
#pragma unroll
    for (int kk = 0; kk < BKK; ++kk) {
      float4 a = *(const float4*)&As[kk][ty << 2];
      float4 b = *(const float4*)&Bs[kk][tx << 2];
      acc[0][0] += a.x * b.x; acc[0][1] += a.x * b.y; acc[0][2] += a.x * b.z; acc[0][3] += a.x * b.w;
      acc[1][0] += a.y * b.x; acc[1][1] += a.y * b.y; acc[1][2] += a.y * b.z; acc[1][3] += a.y * b.w;
      acc[2][0] += a.z * b.x; acc[2][1] += a.z * b.y; acc[2][2] += a.z * b.z; acc[2][3] += a.z * b.w;
      acc[3][0] += a.w * b.x; acc[3][1] += a.w * b.y; acc[3][2] += a.w * b.z; acc[3][3] += a.w * b.w;
    }
    __syncthreads();
  }
  const float* b2e = b2 + (size_t)eg * DIM;
  const float4 bb = *(const float4*)(b2e + bn + (tx << 2));
#pragma unroll
  for (int r = 0; r < 4; ++r) {
    int rr = m0 + (ty << 2) + r;
    if (rr < rows) {
      float4 o;
      o.x = acc[r][0] + bb.x; o.y = acc[r][1] + bb.y;
      o.z = acc[r][2] + bb.z; o.w = acc[r][3] + bb.w;
      *(float4*)(y + (size_t)(r0 + rr) * DIM + bn + (tx << 2)) = o;
    }
  }
}

// ---------------- combine top-2 experts + residual + LN2 ----------------
__global__ __launch_bounds__(256) void k_moe_combine_ln(const float* __restrict__ xin,
                                                        const float* __restrict__ y,
                                                        const float* __restrict__ topw,
                                                        const int* __restrict__ slot_of,
                                                        const float* __restrict__ g,
                                                        const float* __restrict__ bt,
                                                        float* __restrict__ xout) {
  __shared__ float red[256];
  const int t = blockIdx.x, tid = threadIdx.x;
  const float w0 = topw[2 * t], w1v = topw[2 * t + 1];
  const int s0 = slot_of[2 * t], s1 = slot_of[2 * t + 1];
  const size_t base = (size_t)t * DIM;
  float v[4];
  float s = 0.f;
#pragma unroll
  for (int j = 0; j < 4; ++j) {
    int d = tid + 256 * j;
    v[j] = xin[base + d] + w0 * y[(size_t)s0 * DIM + d] + w1v * y[(size_t)s1 * DIM + d];
    s += v[j];
  }
  float mean = block_reduce_sum(s, red) * (1.0f / DIM);
  float s2 = 0.f;
#pragma unroll
  for (int j = 0; j < 4; ++j) { float dv = v[j] - mean; s2 += dv * dv; }
  float var = block_reduce_sum(s2, red) * (1.0f / DIM);
  float rs = rsqrtf(var + 1e-5f);
#pragma unroll
  for (int j = 0; j < 4; ++j) {
    int d = tid + 256 * j;
    xout[base + d] = (v[j] - mean) * rs * g[d] + bt[d];
  }
}

// ---------------- mean-pool over seq + classifier ----------------
__global__ __launch_bounds__(256) void k_pool_cls(const float* __restrict__ x,
                                                  const float* __restrict__ cw,
                                                  const float* __restrict__ cb,
                                                  float* __restrict__ out) {
  __shared__ float pooled[DIM];
  const int b = blockIdx.x, tid = threadIdx.x;
  float a[4] = {0.f, 0.f, 0.f, 0.f};
  for (int s = 0; s < SEQ; ++s) {
    const float* row = x + (size_t)(b * SEQ + s) * DIM;
#pragma unroll
    for (int j = 0; j < 4; ++j) a[j] += row[tid + 256 * j];
  }
#pragma unroll
  for (int j = 0; j < 4; ++j) pooled[tid + 256 * j] = a[j] * (1.0f / SEQ);
  __syncthreads();
  const int wv = tid >> 6, lane = tid & 63;
  for (int c = wv; c < NCLS; c += 4) {
    float p = 0.f;
    for (int d = lane; d < DIM; d += 64) p += pooled[d] * cw[(size_t)c * DIM + d];
    for (int m = 32; m; m >>= 1) p += __shfl_xor(p, m);
    if (lane == 0) out[b * NCLS + c] = p + cb[c];
  }
}

extern "C" void kernel_launch(void* const* d_in, const int* in_sizes, int n_in,
                              void* d_out, int out_size, void* d_ws, size_t ws_size,
                              hipStream_t stream) {
  const int*   src  = (const int*)  d_in[0];
  const float* emb  = (const float*)d_in[1];
  const float* ipw  = (const float*)d_in[2];
  const float* ipb  = (const float*)d_in[3];
  const float* ow   = (const float*)d_in[4];
  const float* ob   = (const float*)d_in[5];
  const float* ln1g = (const float*)d_in[6];
  const float* ln1b = (const float*)d_in[7];
  const float* ln2g = (const float*)d_in[8];
  const float* ln2b = (const float*)d_in[9];
  const float* gw   = (const float*)d_in[10];
  const float* gb   = (const float*)d_in[11];
  const float* w1   = (const float*)d_in[12];
  const float* b1   = (const float*)d_in[13];
  const float* w2   = (const float*)d_in[14];
  const float* b2   = (const float*)d_in[15];
  const float* cw   = (const float*)d_in[16];
  const float* cb   = (const float*)d_in[17];
  float* out = (float*)d_out;

  char* ws = (char*)d_ws;
  size_t off = 0;
  auto carve = [&](size_t bytes) -> void* {
    void* p = ws + off;
    off += (bytes + 255) & ~(size_t)255;
    return p;
  };
  float* x          = (float*)carve((size_t)TKN * DIM * 4);
  float* qkv        = (float*)carve((size_t)TKN * 3 * DIM * 4);
  float* attno      = (float*)carve((size_t)TKN * DIM * 4);
  float* proj       = (float*)carve((size_t)TKN * DIM * 4);
  float* hbuf       = (float*)carve((size_t)TKN * TOPK * HFF * 4);
  float* ybuf       = (float*)carve((size_t)TKN * TOPK * DIM * 4);
  float* topw       = (float*)carve((size_t)TKN * TOPK * 4);
  int*   topi       = (int*)  carve((size_t)TKN * TOPK * 4);
  int*   slot_token = (int*)  carve((size_t)TKN * TOPK * 4);
  int*   slot_of    = (int*)  carve((size_t)TKN * TOPK * 4);
  int*   offg       = (int*)  carve(64);

  k_embed<<<TKN, 256, 0, stream>>>(src, emb, x);
  for (int l = 0; l < NLAYER; ++l) {
    k_gemm_bt<<<dim3(3 * DIM / BN, TKN / BM), 256, 0, stream>>>(
        x, ipw + (size_t)l * 3 * DIM * DIM, ipb + (size_t)l * 3 * DIM, qkv, TKN, 3 * DIM, DIM);
    k_attn<<<dim3(SEQ / 16, NHEAD, BATCH), 256, 0, stream>>>(qkv, attno);
    k_gemm_bt<<<dim3(DIM / BN, TKN / BM), 256, 0, stream>>>(
        attno, ow + (size_t)l * DIM * DIM, ob + (size_t)l * DIM, proj, TKN, DIM, DIM);
    k_add_ln<<<TKN, 256, 0, stream>>>(x, proj, ln1g + l * DIM, ln1b + l * DIM, x);
    k_gate<<<TKN, 256, 0, stream>>>(x, gw + (size_t)l * NE * DIM, gb + l * NE,
                                    out + 80 + (size_t)l * TKN * NE, topi, topw);
    k_route<<<1, 512, 0, stream>>>(topi, offg, slot_token, slot_of);
    k_moe_gemm1<<<dim3(HFF / BN, TKN / BM, NE), 256, 0, stream>>>(
        x, w1 + (size_t)l * NE * DIM * HFF, b1 + (size_t)l * NE * HFF, slot_token, offg, hbuf);
    k_moe_gemm2<<<dim3(DIM / BN, TKN / BM, NE), 256, 0, stream>>>(
        hbuf, w2 + (size_t)l * NE * HFF * DIM, b2 + (size_t)l * NE * DIM, offg, ybuf);
    k_moe_combine_ln<<<TKN, 256, 0, stream>>>(x, ybuf, topw, slot_of,
                                              ln2g + l * DIM, ln2b + l * DIM, x);
  }
  k_pool_cls<<<BATCH, 256, 0, stream>>>(x, cw, cb, out);
}

// Round 3
// 1750.864 us; speedup vs baseline: 2.3116x; 2.3116x over previous
//
#include <hip/hip_runtime.h>
#include <math.h>

#define TKN 2048
#define DIM 1024
#define NHEAD 16
#define HDIM 64
#define HFF 2048
#define NE 8
#define TOPK 2
#define NCLS 10
#define NLAYER 4
#define SEQ 256
#define BATCH 8

typedef __attribute__((ext_vector_type(8))) _Float16 f16x8;
typedef __attribute__((ext_vector_type(4))) float f32x4;

__device__ __forceinline__ unsigned short f2h(float v) {
  _Float16 h = (_Float16)v;
  return __builtin_bit_cast(unsigned short, h);
}
__device__ __forceinline__ float h2f(unsigned short u) {
  return (float)__builtin_bit_cast(_Float16, u);
}
__device__ __forceinline__ void fsplit(float v, unsigned short& hi, unsigned short& lo) {
  _Float16 h = (_Float16)v;
  hi = __builtin_bit_cast(unsigned short, h);
  lo = f2h(v - (float)h);
}

__device__ __forceinline__ void gload_lds16(const void* g, void* l) {
  __builtin_amdgcn_global_load_lds((__attribute__((address_space(1))) void*)g,
                                   (__attribute__((address_space(3))) void*)l,
                                   16, 0, 0);
}

// ---------------- embed + positional encoding (fp32 + f16 hi/lo out) ----------------
__global__ __launch_bounds__(256) void k_embed(const int* __restrict__ src,
                                               const float* __restrict__ emb,
                                               float* __restrict__ x,
                                               unsigned short* __restrict__ xhi,
                                               unsigned short* __restrict__ xlo) {
  const int t = blockIdx.x;
  const int tid = threadIdx.x;
  const int b = t / SEQ;
  const int tok = src[t];
  const float* erow = emb + (size_t)tok * DIM;
  const size_t base = (size_t)t * DIM;
  const float cexp = -9.210340371976184f / 1024.0f;  // -ln(10000)/D
#pragma unroll
  for (int j = 0; j < 4; ++j) {
    int d = tid + 256 * j;
    int i2 = d & ~1;
    float ang = (float)b * expf((float)i2 * cexp);
    float pe = (d & 1) ? cosf(ang) : sinf(ang);
    float v = erow[d] * 32.0f + pe;
    x[base + d] = v;
    fsplit(v, xhi[base + d], xlo[base + d]);
  }
}

// ---------------- fp32 -> f16 hi/lo planes ----------------
__global__ __launch_bounds__(256) void k_cvt_split(const float* __restrict__ in,
                                                   unsigned short* __restrict__ ohi,
                                                   unsigned short* __restrict__ olo) {
  int i = blockIdx.x * 256 + threadIdx.x;
  float4 v = ((const float4*)in)[i];
  ushort4 h, l;
  fsplit(v.x, h.x, l.x); fsplit(v.y, h.y, l.y);
  fsplit(v.z, h.z, l.z); fsplit(v.w, h.w, l.w);
  ((ushort4*)ohi)[i] = h;
  ((ushort4*)olo)[i] = l;
}

// ---------------- transpose + split: in [R][Cc] f32 -> out [Cc][R] f16 hi/lo ----------------
__global__ __launch_bounds__(256) void k_cvt_t_split(const float* __restrict__ in,
                                                     unsigned short* __restrict__ ohi,
                                                     unsigned short* __restrict__ olo,
                                                     int R, int Cc) {
  __shared__ float t[32][33];
  const int tx = threadIdx.x & 31, ty = threadIdx.x >> 5;  // 32 x 8
  const int c0 = blockIdx.x * 32, r0 = blockIdx.y * 32;
  const float* ip = in + (size_t)blockIdx.z * R * Cc;
  const size_t obase = (size_t)blockIdx.z * R * Cc;
#pragma unroll
  for (int j = 0; j < 4; ++j)
    t[ty + 8 * j][tx] = ip[(size_t)(r0 + ty + 8 * j) * Cc + c0 + tx];
  __syncthreads();
#pragma unroll
  for (int j = 0; j < 4; ++j) {
    unsigned short hi, lo;
    fsplit(t[tx][ty + 8 * j], hi, lo);
    size_t o = obase + (size_t)(c0 + ty + 8 * j) * R + r0 + tx;
    ohi[o] = hi;
    olo[o] = lo;
  }
}

// ---------------- compensated f16 MFMA GEMM: C[M,N] = A[M,K] * B[N,K]^T + bias ----------------
// MODE 0: dense. MODE 1: MoE gather (A rows via slot_token). MODE 2: MoE contig.
// OUTK 0: fp32 out0. 1: f16-hi out0. 2: f16 hi out0 + lo out1.
// SPLIT: 3-pass compensated (hi*hi + hi*lo + lo*hi) vs single-pass hi*hi.
template <int MODE, bool RELU, int OUTK, bool SPLIT>
__global__ __launch_bounds__(256) void k_mfma_gemm(
    const unsigned short* __restrict__ Ahi, const unsigned short* __restrict__ Alo,
    const unsigned short* __restrict__ Bhi, const unsigned short* __restrict__ Blo,
    const float* __restrict__ bias, void* __restrict__ out0, void* __restrict__ out1,
    int M, int N, int K,
    const int* __restrict__ slot_token, const int* __restrict__ offg) {
  constexpr int NP = SPLIT ? 2 : 1;
  __shared__ unsigned short As[NP][128][32];
  __shared__ unsigned short Bs[NP][128][32];
  const int tid = threadIdx.x;
  const int w = tid >> 6, lane = tid & 63;
  const int bm = blockIdx.y * 128, bn = blockIdx.x * 128;
  int r0 = 0, rows = M, e = 0;
  if (MODE != 0) {
    e = blockIdx.z;
    r0 = offg[e];
    rows = offg[e + 1] - r0;
    if (bm >= rows) return;
  }
  const size_t bwb = (size_t)e * K * N;
  const float* biasq = bias + (size_t)e * N;

  const int srow = lane >> 2;       // 0..15
  const int skof = (lane & 3) * 8;  // k elem offset (16B per lane)
  const unsigned short *ah[2], *bh[2], *al[2], *bl[2];
#pragma unroll
  for (int q = 0; q < 2; ++q) {
    int rloc = w * 32 + q * 16 + srow;
    int grow;
    if (MODE == 0) {
      grow = bm + rloc;
    } else {
      int rr = bm + rloc;
      if (rr >= rows) rr = rows - 1;
      grow = (MODE == 1) ? slot_token[r0 + rr] : (r0 + rr);
    }
    size_t ao = (size_t)grow * K + skof;
    size_t bo = bwb + (size_t)(bn + rloc) * K + skof;
    ah[q] = Ahi + ao; bh[q] = Bhi + bo;
    if (SPLIT) { al[q] = Alo + ao; bl[q] = Blo + bo; }
  }

  f32x4 acc[4][4] = {};
  const int wr = w >> 1, wc = w & 1;
  const int lr = lane & 15, lg = lane >> 4;

  for (int k0 = 0; k0 < K; k0 += 32) {
#pragma unroll
    for (int q = 0; q < 2; ++q) {
      const int rb = w * 32 + q * 16;
      gload_lds16(ah[q], &As[0][rb][0]);
      gload_lds16(bh[q], &Bs[0][rb][0]);
      ah[q] += 32; bh[q] += 32;
      if constexpr (SPLIT) {
        gload_lds16(al[q], &As[1][rb][0]);
        gload_lds16(bl[q], &Bs[1][rb][0]);
        al[q] += 32; bl[q] += 32;
      }
    }
    __syncthreads();  // drains vmcnt: LDS tiles ready
    f16x8 afh[4], bfh[4], afl[4], bfl[4];
#pragma unroll
    for (int m = 0; m < 4; ++m)
      afh[m] = *(const f16x8*)&As[0][wr * 64 + m * 16 + lr][lg * 8];
#pragma unroll
    for (int n = 0; n < 4; ++n)
      bfh[n] = *(const f16x8*)&Bs[0][wc * 64 + n * 16 + lr][lg * 8];
    if constexpr (SPLIT) {
#pragma unroll
      for (int m = 0; m < 4; ++m)
        afl[m] = *(const f16x8*)&As[1][wr * 64 + m * 16 + lr][lg * 8];
#pragma unroll
      for (int n = 0; n < 4; ++n)
        bfl[n] = *(const f16x8*)&Bs[1][wc * 64 + n * 16 + lr][lg * 8];
    }
#pragma unroll
    for (int m = 0; m < 4; ++m)
#pragma unroll
      for (int n = 0; n < 4; ++n) {
        acc[m][n] = __builtin_amdgcn_mfma_f32_16x16x32_f16(afh[m], bfh[n], acc[m][n], 0, 0, 0);
        if constexpr (SPLIT) {
          acc[m][n] = __builtin_amdgcn_mfma_f32_16x16x32_f16(afh[m], bfl[n], acc[m][n], 0, 0, 0);
          acc[m][n] = __builtin_amdgcn_mfma_f32_16x16x32_f16(afl[m], bfh[n], acc[m][n], 0, 0, 0);
        }
      }
    __syncthreads();  // all reads done before next stage overwrites
  }

  float bv[4];
#pragma unroll
  for (int n = 0; n < 4; ++n) bv[n] = biasq[bn + wc * 64 + n * 16 + lr];

#pragma unroll
  for (int m = 0; m < 4; ++m) {
#pragma unroll
    for (int j = 0; j < 4; ++j) {
      int rowg = bm + wr * 64 + m * 16 + lg * 4 + j;
      if (MODE != 0 && rowg >= rows) continue;
      size_t crow = (size_t)((MODE == 0) ? rowg : (r0 + rowg)) * N;
#pragma unroll
      for (int n = 0; n < 4; ++n) {
        float v = acc[m][n][j] + bv[n];
        if (RELU) v = fmaxf(v, 0.f);
        size_t o = crow + bn + wc * 64 + n * 16 + lr;
        if (OUTK == 0) {
          ((float*)out0)[o] = v;
        } else if (OUTK == 1) {
          ((unsigned short*)out0)[o] = f2h(v);
        } else {
          unsigned short hi, lo;
          fsplit(v, hi, lo);
          ((unsigned short*)out0)[o] = hi;
          ((unsigned short*)out1)[o] = lo;
        }
      }
    }
  }
}

// ---------------- attention: 16 q-rows per block (fp32 in, f16 hi/lo out) ----------------
__global__ __launch_bounds__(256) void k_attn(const float* __restrict__ qkv,
                                              unsigned short* __restrict__ ohi,
                                              unsigned short* __restrict__ olo) {
  const int qt = blockIdx.x;
  const int hh = blockIdx.y;
  const int bb = blockIdx.z;
  const int tid = threadIdx.x;
  __shared__ float qs[16][64];
  __shared__ float ps[16][256];
  const int t0 = bb * SEQ + qt * 16;
  for (int i = tid; i < 16 * 64; i += 256) {
    int qi = i >> 6, d = i & 63;
    qs[qi][d] = qkv[(size_t)(t0 + qi) * (3 * DIM) + hh * 64 + d];
  }
  __syncthreads();
  float s[16];
#pragma unroll
  for (int qi = 0; qi < 16; ++qi) s[qi] = 0.f;
  const float* krow = qkv + (size_t)(bb * SEQ + tid) * (3 * DIM) + DIM + hh * 64;
#pragma unroll 4
  for (int c = 0; c < 16; ++c) {
    float4 kv = *(const float4*)(krow + c * 4);
#pragma unroll
    for (int qi = 0; qi < 16; ++qi) {
      s[qi] += kv.x * qs[qi][c * 4 + 0] + kv.y * qs[qi][c * 4 + 1] +
               kv.z * qs[qi][c * 4 + 2] + kv.w * qs[qi][c * 4 + 3];
    }
  }
#pragma unroll
  for (int qi = 0; qi < 16; ++qi) ps[qi][tid] = s[qi] * 0.125f;
  __syncthreads();
  const int wv = tid >> 6, lane = tid & 63;
  for (int rr = wv; rr < 16; rr += 4) {
    float v[4];
#pragma unroll
    for (int j = 0; j < 4; ++j) v[j] = ps[rr][lane + 64 * j];
    float m = fmaxf(fmaxf(v[0], v[1]), fmaxf(v[2], v[3]));
    for (int msk = 32; msk; msk >>= 1) m = fmaxf(m, __shfl_xor(m, msk));
    float e[4], sum = 0.f;
#pragma unroll
    for (int j = 0; j < 4; ++j) { e[j] = expf(v[j] - m); sum += e[j]; }
    for (int msk = 32; msk; msk >>= 1) sum += __shfl_xor(sum, msk);
    float inv = 1.0f / sum;
#pragma unroll
    for (int j = 0; j < 4; ++j) ps[rr][lane + 64 * j] = e[j] * inv;
  }
  __syncthreads();
  const int qi0 = tid >> 6, d = tid & 63;
  float acc[4] = {0.f, 0.f, 0.f, 0.f};
  const float* vbase = qkv + (size_t)(bb * SEQ) * (3 * DIM) + 2 * DIM + hh * 64 + d;
  for (int k = 0; k < 256; ++k) {
    float vv = vbase[(size_t)k * (3 * DIM)];
    acc[0] += ps[qi0][k] * vv;
    acc[1] += ps[qi0 + 4][k] * vv;
    acc[2] += ps[qi0 + 8][k] * vv;
    acc[3] += ps[qi0 + 12][k] * vv;
  }
#pragma unroll
  for (int j = 0; j < 4; ++j) {
    size_t o = (size_t)(t0 + qi0 + 4 * j) * DIM + hh * 64 + d;
    fsplit(acc[j], ohi[o], olo[o]);
  }
}

// ---------------- block reduce helper ----------------
__device__ __forceinline__ float block_reduce_sum(float v, float* red) {
  const int tid = threadIdx.x;
  red[tid] = v;
  __syncthreads();
  for (int s = 128; s > 0; s >>= 1) {
    if (tid < s) red[tid] += red[tid + s];
    __syncthreads();
  }
  float r = red[0];
  __syncthreads();
  return r;
}

// ---------------- x = LN(xin + add), fp32 + f16 hi/lo out ----------------
__global__ __launch_bounds__(256) void k_add_ln(const float* __restrict__ xin,
                                                const float* __restrict__ add,
                                                const float* __restrict__ g,
                                                const float* __restrict__ bt,
                                                float* __restrict__ xout,
                                                unsigned short* __restrict__ xhi,
                                                unsigned short* __restrict__ xlo) {
  __shared__ float red[256];
  const int t = blockIdx.x, tid = threadIdx.x;
  const size_t base = (size_t)t * DIM;
  float v[4];
  float s = 0.f;
#pragma unroll
  for (int j = 0; j < 4; ++j) {
    int d = tid + 256 * j;
    v[j] = xin[base + d] + add[base + d];
    s += v[j];
  }
  float mean = block_reduce_sum(s, red) * (1.0f / DIM);
  float s2 = 0.f;
#pragma unroll
  for (int j = 0; j < 4; ++j) { float dv = v[j] - mean; s2 += dv * dv; }
  float var = block_reduce_sum(s2, red) * (1.0f / DIM);
  float rs = rsqrtf(var + 1e-5f);
#pragma unroll
  for (int j = 0; j < 4; ++j) {
    int d = tid + 256 * j;
    float o = (v[j] - mean) * rs * g[d] + bt[d];
    xout[base + d] = o;
    fsplit(o, xhi[base + d], xlo[base + d]);
  }
}

// ---------------- gate: logits (to d_out), top-2 + softmax weights ----------------
__global__ __launch_bounds__(256) void k_gate(const float* __restrict__ x,
                                              const float* __restrict__ gw,
                                              const float* __restrict__ gb,
                                              float* __restrict__ gout,
                                              int* __restrict__ topi,
                                              float* __restrict__ topw) {
  __shared__ float xs[DIM];
  __shared__ float lgs[NE];
  const int t = blockIdx.x, tid = threadIdx.x;
#pragma unroll
  for (int j = 0; j < 4; ++j) xs[tid + 256 * j] = x[(size_t)t * DIM + tid + 256 * j];
  __syncthreads();
  const int eg = tid >> 5, l32 = tid & 31;
  const float* wrow = gw + (size_t)eg * DIM;
  float p = 0.f;
  for (int j = 0; j < 32; ++j) {
    int d = l32 + 32 * j;
    p += xs[d] * wrow[d];
  }
  for (int m = 16; m; m >>= 1) p += __shfl_xor(p, m);
  if (l32 == 0) lgs[eg] = p;
  __syncthreads();
  if (tid < NE) {
    float v = lgs[tid] + gb[tid];
    gout[(size_t)t * NE + tid] = v;
    lgs[tid] = v;
  }
  __syncthreads();
  if (tid == 0) {
    int i0 = 0; float v0 = lgs[0];
    for (int i = 1; i < NE; ++i) if (lgs[i] > v0) { v0 = lgs[i]; i0 = i; }
    int i1 = -1; float v1 = -1e30f;
    for (int i = 0; i < NE; ++i) { if (i == i0) continue; if (lgs[i] > v1) { v1 = lgs[i]; i1 = i; } }
    float e1 = expf(v1 - v0);
    float w0 = 1.0f / (1.0f + e1);
    topi[2 * t] = i0; topi[2 * t + 1] = i1;
    topw[2 * t] = w0; topw[2 * t + 1] = e1 * w0;
  }
}

// ---------------- deterministic routing build ----------------
__global__ __launch_bounds__(512) void k_route(const int* __restrict__ topi,
                                               int* __restrict__ offg,
                                               int* __restrict__ slot_token,
                                               int* __restrict__ slot_of) {
  __shared__ int cnt_s[NE];
  __shared__ int off_s[NE + 1];
  const int tid = threadIdx.x;
  const int w = tid >> 6, lane = tid & 63;
  int c = 0;
  for (int i = lane; i < TKN * TOPK; i += 64) c += (topi[i] == w) ? 1 : 0;
  for (int m = 32; m; m >>= 1) c += __shfl_xor(c, m);
  if (lane == 0) cnt_s[w] = c;
  __syncthreads();
  if (tid == 0) {
    off_s[0] = 0;
    for (int e2 = 0; e2 < NE; ++e2) off_s[e2 + 1] = off_s[e2] + cnt_s[e2];
    for (int e2 = 0; e2 <= NE; ++e2) offg[e2] = off_s[e2];
  }
  __syncthreads();
  int base = off_s[w];
  for (int i0 = 0; i0 < TKN * TOPK; i0 += 64) {
    int i = i0 + lane;
    bool mm = (topi[i] == w);
    unsigned long long mask = __ballot(mm ? 1 : 0);
    int rank = __popcll(mask & ((1ull << lane) - 1ull));
    if (mm) {
      int slot = base + rank;
      slot_token[slot] = i >> 1;
      slot_of[i] = slot;
    }
    base += __popcll(mask);
  }
}

// ---------------- combine top-2 experts + residual + LN2 (fp32 + hi/lo out) ----------------
__global__ __launch_bounds__(256) void k_moe_combine_ln(const float* __restrict__ xin,
                                                        const float* __restrict__ y,
                                                        const float* __restrict__ topw,
                                                        const int* __restrict__ slot_of,
                                                        const float* __restrict__ g,
                                                        const float* __restrict__ bt,
                                                        float* __restrict__ xout,
                                                        unsigned short* __restrict__ xhi,
                                                        unsigned short* __restrict__ xlo) {
  __shared__ float red[256];
  const int t = blockIdx.x, tid = threadIdx.x;
  const float w0 = topw[2 * t], w1v = topw[2 * t + 1];
  const int s0 = slot_of[2 * t], s1 = slot_of[2 * t + 1];
  const size_t base = (size_t)t * DIM;
  float v[4];
  float s = 0.f;
#pragma unroll
  for (int j = 0; j < 4; ++j) {
    int d = tid + 256 * j;
    v[j] = xin[base + d] + w0 * y[(size_t)s0 * DIM + d] + w1v * y[(size_t)s1 * DIM + d];
    s += v[j];
  }
  float mean = block_reduce_sum(s, red) * (1.0f / DIM);
  float s2 = 0.f;
#pragma unroll
  for (int j = 0; j < 4; ++j) { float dv = v[j] - mean; s2 += dv * dv; }
  float var = block_reduce_sum(s2, red) * (1.0f / DIM);
  float rs = rsqrtf(var + 1e-5f);
#pragma unroll
  for (int j = 0; j < 4; ++j) {
    int d = tid + 256 * j;
    float o = (v[j] - mean) * rs * g[d] + bt[d];
    xout[base + d] = o;
    fsplit(o, xhi[base + d], xlo[base + d]);
  }
}

// ---------------- mean-pool over seq + classifier ----------------
__global__ __launch_bounds__(256) void k_pool_cls(const float* __restrict__ x,
                                                  const float* __restrict__ cw,
                                                  const float* __restrict__ cb,
                                                  float* __restrict__ out) {
  __shared__ float pooled[DIM];
  const int b = blockIdx.x, tid = threadIdx.x;
  float a[4] = {0.f, 0.f, 0.f, 0.f};
  for (int s = 0; s < SEQ; ++s) {
    const float* row = x + (size_t)(b * SEQ + s) * DIM;
#pragma unroll
    for (int j = 0; j < 4; ++j) a[j] += row[tid + 256 * j];
  }
#pragma unroll
  for (int j = 0; j < 4; ++j) pooled[tid + 256 * j] = a[j] * (1.0f / SEQ);
  __syncthreads();
  const int wv = tid >> 6, lane = tid & 63;
  for (int c = wv; c < NCLS; c += 4) {
    float p = 0.f;
    for (int d = lane; d < DIM; d += 64) p += pooled[d] * cw[(size_t)c * DIM + d];
    for (int m = 32; m; m >>= 1) p += __shfl_xor(p, m);
    if (lane == 0) out[b * NCLS + c] = p + cb[c];
  }
}

extern "C" void kernel_launch(void* const* d_in, const int* in_sizes, int n_in,
                              void* d_out, int out_size, void* d_ws, size_t ws_size,
                              hipStream_t stream) {
  const int*   src  = (const int*)  d_in[0];
  const float* emb  = (const float*)d_in[1];
  const float* ipw  = (const float*)d_in[2];
  const float* ipb  = (const float*)d_in[3];
  const float* ow   = (const float*)d_in[4];
  const float* ob   = (const float*)d_in[5];
  const float* ln1g = (const float*)d_in[6];
  const float* ln1b = (const float*)d_in[7];
  const float* ln2g = (const float*)d_in[8];
  const float* ln2b = (const float*)d_in[9];
  const float* gw   = (const float*)d_in[10];
  const float* gb   = (const float*)d_in[11];
  const float* w1   = (const float*)d_in[12];
  const float* b1   = (const float*)d_in[13];
  const float* w2   = (const float*)d_in[14];
  const float* b2   = (const float*)d_in[15];
  const float* cw   = (const float*)d_in[16];
  const float* cb   = (const float*)d_in[17];
  float* out = (float*)d_out;

  char* ws = (char*)d_ws;
  size_t off = 0;
  auto carve = [&](size_t bytes) -> void* {
    void* p = ws + off;
    off += (bytes + 255) & ~(size_t)255;
    return p;
  };
  float*          x     = (float*)carve((size_t)TKN * DIM * 4);
  unsigned short* xhi   = (unsigned short*)carve((size_t)TKN * DIM * 2);
  unsigned short* xlo   = (unsigned short*)carve((size_t)TKN * DIM * 2);
  // qkv fp32 (25.2MB) overlaps h hi+lo planes (2x16.8MB); qkv dead after attn
  char*           bufQ  = (char*)carve((size_t)2 * TKN * TOPK * HFF * 2);
  float*          qkv   = (float*)bufQ;
  unsigned short* h_hi  = (unsigned short*)bufQ;
  unsigned short* h_lo  = (unsigned short*)(bufQ + (size_t)TKN * TOPK * HFF * 2);
  unsigned short* at_hi = (unsigned short*)carve((size_t)TKN * DIM * 2);
  unsigned short* at_lo = (unsigned short*)carve((size_t)TKN * DIM * 2);
  // proj fp32 (8.4MB) overlaps ybuf fp32 (16.8MB); proj dead after add_ln
  char*           bufP  = (char*)carve((size_t)TKN * TOPK * DIM * 4);
  float*          proj  = (float*)bufP;
  float*          ybuf  = (float*)bufP;
  unsigned short* wq_hi = (unsigned short*)carve((size_t)3 * DIM * DIM * 2);
  unsigned short* wq_lo = (unsigned short*)carve((size_t)3 * DIM * DIM * 2);
  unsigned short* wo_hi = (unsigned short*)carve((size_t)DIM * DIM * 2);
  unsigned short* wo_lo = (unsigned short*)carve((size_t)DIM * DIM * 2);
  // w1t / w2t share (sequential use within a layer)
  unsigned short* wt_hi = (unsigned short*)carve((size_t)NE * DIM * HFF * 2);
  unsigned short* wt_lo = (unsigned short*)carve((size_t)NE * DIM * HFF * 2);
  float* topw       = (float*)carve((size_t)TKN * TOPK * 4);
  int*   topi       = (int*)  carve((size_t)TKN * TOPK * 4);
  int*   slot_token = (int*)  carve((size_t)TKN * TOPK * 4);
  int*   slot_of    = (int*)  carve((size_t)TKN * TOPK * 4);
  int*   offg       = (int*)  carve(64);

  k_embed<<<TKN, 256, 0, stream>>>(src, emb, x, xhi, xlo);

  for (int l = 0; l < NLAYER; ++l) {
    const float* ipw_l = ipw + (size_t)l * 3 * DIM * DIM;
    const float* ow_l  = ow  + (size_t)l * DIM * DIM;
    const float* w1_l  = w1  + (size_t)l * NE * DIM * HFF;
    const float* w2_l  = w2  + (size_t)l * NE * HFF * DIM;
    const bool sp = (l < NLAYER - 1);  // layer 3: single-pass (flips only touch pooled cls)

    k_cvt_split<<<(3 * DIM * DIM) / 1024, 256, 0, stream>>>(ipw_l, wq_hi, wq_lo);
    k_cvt_split<<<(DIM * DIM) / 1024, 256, 0, stream>>>(ow_l, wo_hi, wo_lo);
    k_cvt_t_split<<<dim3(HFF / 32, DIM / 32, NE), 256, 0, stream>>>(w1_l, wt_hi, wt_lo, DIM, HFF);

    // QKV: [2048,1024] x [3072,1024]^T -> qkv fp32
    if (sp)
      k_mfma_gemm<0, false, 0, true><<<dim3(3 * DIM / 128, TKN / 128), 256, 0, stream>>>(
          xhi, xlo, wq_hi, wq_lo, ipb + (size_t)l * 3 * DIM, qkv, nullptr, TKN, 3 * DIM, DIM, nullptr, nullptr);
    else
      k_mfma_gemm<0, false, 0, false><<<dim3(3 * DIM / 128, TKN / 128), 256, 0, stream>>>(
          xhi, xlo, wq_hi, wq_lo, ipb + (size_t)l * 3 * DIM, qkv, nullptr, TKN, 3 * DIM, DIM, nullptr, nullptr);

    k_attn<<<dim3(SEQ / 16, NHEAD, BATCH), 256, 0, stream>>>(qkv, at_hi, at_lo);

    // out-projection -> proj fp32
    if (sp)
      k_mfma_gemm<0, false, 0, true><<<dim3(DIM / 128, TKN / 128), 256, 0, stream>>>(
          at_hi, at_lo, wo_hi, wo_lo, ob + (size_t)l * DIM, proj, nullptr, TKN, DIM, DIM, nullptr, nullptr);
    else
      k_mfma_gemm<0, false, 0, false><<<dim3(DIM / 128, TKN / 128), 256, 0, stream>>>(
          at_hi, at_lo, wo_hi, wo_lo, ob + (size_t)l * DIM, proj, nullptr, TKN, DIM, DIM, nullptr, nullptr);

    k_add_ln<<<TKN, 256, 0, stream>>>(x, proj, ln1g + l * DIM, ln1b + l * DIM, x, xhi, xlo);

    k_gate<<<TKN, 256, 0, stream>>>(x, gw + (size_t)l * NE * DIM, gb + l * NE,
                                    out + NCLS * BATCH + (size_t)l * TKN * NE, topi, topw);
    k_route<<<1, 512, 0, stream>>>(topi, offg, slot_token, slot_of);

    // expert GEMM1 (gather): h = relu(x[tok] @ w1t^T + b1)
    if (sp)
      k_mfma_gemm<1, true, 2, true><<<dim3(HFF / 128, TKN * TOPK / 128, NE), 256, 0, stream>>>(
          xhi, xlo, wt_hi, wt_lo, b1 + (size_t)l * NE * HFF, h_hi, h_lo, 0, HFF, DIM, slot_token, offg);
    else
      k_mfma_gemm<1, true, 1, false><<<dim3(HFF / 128, TKN * TOPK / 128, NE), 256, 0, stream>>>(
          xhi, xlo, wt_hi, wt_lo, b1 + (size_t)l * NE * HFF, h_hi, nullptr, 0, HFF, DIM, slot_token, offg);

    // convert w2 (w1t dead after gemm1)
    k_cvt_t_split<<<dim3(DIM / 32, HFF / 32, NE), 256, 0, stream>>>(w2_l, wt_hi, wt_lo, HFF, DIM);

    // expert GEMM2: y = h @ w2t^T + b2, fp32 out
    if (sp)
      k_mfma_gemm<2, false, 0, true><<<dim3(DIM / 128, TKN * TOPK / 128, NE), 256, 0, stream>>>(
          h_hi, h_lo, wt_hi, wt_lo, b2 + (size_t)l * NE * DIM, ybuf, nullptr, 0, DIM, HFF, nullptr, offg);
    else
      k_mfma_gemm<2, false, 0, false><<<dim3(DIM / 128, TKN * TOPK / 128, NE), 256, 0, stream>>>(
          h_hi, h_lo, wt_hi, wt_lo, b2 + (size_t)l * NE * DIM, ybuf, nullptr, 0, DIM, HFF, nullptr, offg);

    k_moe_combine_ln<<<TKN, 256, 0, stream>>>(x, ybuf, topw, slot_of,
                                              ln2g + l * DIM, ln2b + l * DIM, x, xhi, xlo);
  }
  k_pool_cls<<<BATCH, 256, 0, stream>>>(x, cw, cb, out);
}

// Round 4
// 1740.614 us; speedup vs baseline: 2.3252x; 1.0059x over previous
//
#include <hip/hip_runtime.h>
#include <math.h>

#define TKN 2048
#define DIM 1024
#define NHEAD 16
#define HDIM 64
#define HFF 2048
#define NE 8
#define TOPK 2
#define NCLS 10
#define NLAYER 4
#define SEQ 256
#define BATCH 8

typedef __attribute__((ext_vector_type(8))) _Float16 f16x8;
typedef __attribute__((ext_vector_type(4))) float f32x4;

__device__ __forceinline__ unsigned short f2h(float v) {
  _Float16 h = (_Float16)v;
  return __builtin_bit_cast(unsigned short, h);
}
__device__ __forceinline__ float h2f(unsigned short u) {
  return (float)__builtin_bit_cast(_Float16, u);
}
__device__ __forceinline__ void fsplit(float v, unsigned short& hi, unsigned short& lo) {
  _Float16 h = (_Float16)v;
  hi = __builtin_bit_cast(unsigned short, h);
  lo = f2h(v - (float)h);
}

__device__ __forceinline__ void gload_lds16(const void* g, void* l) {
  __builtin_amdgcn_global_load_lds((__attribute__((address_space(1))) void*)g,
                                   (__attribute__((address_space(3))) void*)l,
                                   16, 0, 0);
}

// ---------------- embed + positional encoding (fp32 + f16 hi/lo out) ----------------
__global__ __launch_bounds__(256) void k_embed(const int* __restrict__ src,
                                               const float* __restrict__ emb,
                                               float* __restrict__ x,
                                               unsigned short* __restrict__ xhi,
                                               unsigned short* __restrict__ xlo) {
  const int t = blockIdx.x;
  const int tid = threadIdx.x;
  const int b = t / SEQ;
  const int tok = src[t];
  const float* erow = emb + (size_t)tok * DIM;
  const size_t base = (size_t)t * DIM;
  const float cexp = -9.210340371976184f / 1024.0f;  // -ln(10000)/D
#pragma unroll
  for (int j = 0; j < 4; ++j) {
    int d = tid + 256 * j;
    int i2 = d & ~1;
    float ang = (float)b * expf((float)i2 * cexp);
    float pe = (d & 1) ? cosf(ang) : sinf(ang);
    float v = erow[d] * 32.0f + pe;
    x[base + d] = v;
    fsplit(v, xhi[base + d], xlo[base + d]);
  }
}

// ---------------- fp32 -> f16 hi/lo planes ----------------
__global__ __launch_bounds__(256) void k_cvt_split(const float* __restrict__ in,
                                                   unsigned short* __restrict__ ohi,
                                                   unsigned short* __restrict__ olo) {
  int i = blockIdx.x * 256 + threadIdx.x;
  float4 v = ((const float4*)in)[i];
  ushort4 h, l;
  fsplit(v.x, h.x, l.x); fsplit(v.y, h.y, l.y);
  fsplit(v.z, h.z, l.z); fsplit(v.w, h.w, l.w);
  ((ushort4*)ohi)[i] = h;
  ((ushort4*)olo)[i] = l;
}

// ---------------- transpose + split: in [R][Cc] f32 -> out [Cc][R] f16 hi/lo ----------------
__global__ __launch_bounds__(256) void k_cvt_t_split(const float* __restrict__ in,
                                                     unsigned short* __restrict__ ohi,
                                                     unsigned short* __restrict__ olo,
                                                     int R, int Cc) {
  __shared__ float t[32][33];
  const int tx = threadIdx.x & 31, ty = threadIdx.x >> 5;  // 32 x 8
  const int c0 = blockIdx.x * 32, r0 = blockIdx.y * 32;
  const float* ip = in + (size_t)blockIdx.z * R * Cc;
  const size_t obase = (size_t)blockIdx.z * R * Cc;
#pragma unroll
  for (int j = 0; j < 4; ++j)
    t[ty + 8 * j][tx] = ip[(size_t)(r0 + ty + 8 * j) * Cc + c0 + tx];
  __syncthreads();
#pragma unroll
  for (int j = 0; j < 4; ++j) {
    unsigned short hi, lo;
    fsplit(t[tx][ty + 8 * j], hi, lo);
    size_t o = obase + (size_t)(c0 + ty + 8 * j) * R + r0 + tx;
    ohi[o] = hi;
    olo[o] = lo;
  }
}

// ---------------- compensated f16 MFMA GEMM: C[M,N] = A[M,K] * B[N,K]^T + bias ----------
// MODE 0: dense. MODE 1: MoE gather (A rows via slot_token). MODE 2: MoE contig.
// OUTK 0: fp32 out0. 1: f16-hi out0. 2: f16 hi out0 + lo out1.
// SPLIT: 3-pass compensated (hi*hi + hi*lo + lo*hi) vs single-pass hi*hi.
//
// LDS tiles: [128 rows][8 slots x 16B] with physical_slot = logical_slot ^ (row&7)
// (bank-conflict-free ds_read_b128: 16-lane frag group spreads all 32 banks, 2-way).
// SPLIT: U[0]=A (slots 0-3 hi, 4-7 lo), U[1]=B same. non-SPLIT: U[0] slots 0-3=A-hi,
// 4-7=B-hi. global_load_lds writes lane-linear, so the swizzle is realized by
// pre-swizzling the per-lane GLOBAL source (same XOR on the read side).
template <int MODE, bool RELU, int OUTK, bool SPLIT>
__global__ __launch_bounds__(256) void k_mfma_gemm(
    const unsigned short* __restrict__ Ahi, const unsigned short* __restrict__ Alo,
    const unsigned short* __restrict__ Bhi, const unsigned short* __restrict__ Blo,
    const float* __restrict__ bias, void* __restrict__ out0, void* __restrict__ out1,
    int M, int N, int K,
    const int* __restrict__ slot_token, const int* __restrict__ offg) {
  __shared__ unsigned short U[SPLIT ? 2 : 1][128 * 64];
  const int tid = threadIdx.x;
  const int w = tid >> 6, lane = tid & 63;
  const int bm = blockIdx.y * 128, bn = blockIdx.x * 128;
  int r0 = 0, rows = M, e = 0;
  if (MODE != 0) {
    e = blockIdx.z;
    r0 = offg[e];
    rows = offg[e + 1] - r0;
    if (bm >= rows) return;
  }
  const size_t bwb = (size_t)e * K * N;
  const float* biasq = bias + (size_t)e * N;

  // staging: lane covers (row = wave_base + i*8 + (lane>>3), physical slot lane&7)
  const int lrow8 = lane >> 3;
  const int s = (lane & 7) ^ lrow8;   // logical slot this lane must fetch
  const int chunk = (s & 3) * 8;      // k element offset of the 16B chunk
  const unsigned short* sp0[4];
  const unsigned short* sp1[4];
#pragma unroll
  for (int i = 0; i < 4; ++i) {
    int rloc = w * 32 + i * 8 + lrow8;  // tile row 0..127
    int growA;
    if (MODE == 0) {
      growA = bm + rloc;
    } else {
      int rr = bm + rloc;
      if (rr >= rows) rr = rows - 1;
      growA = (MODE == 1) ? slot_token[r0 + rr] : (r0 + rr);
    }
    size_t aoff = (size_t)growA * K + chunk;
    size_t boff = bwb + (size_t)(bn + rloc) * K + chunk;
    if constexpr (SPLIT) {
      sp0[i] = (s < 4 ? Ahi : Alo) + aoff;
      sp1[i] = (s < 4 ? Bhi : Blo) + boff;
    } else {
      sp0[i] = (s < 4) ? (Ahi + aoff) : (Bhi + boff);
      sp1[i] = nullptr;
    }
  }

  f32x4 acc[4][4] = {};
  const int wr = w >> 1, wc = w & 1;
  const int lr = lane & 15, lg = lane >> 4;
  const int sw = lr & 7;  // (row & 7) for this lane's fragment rows
  unsigned aoffs[4], boffs[4];  // ushort offsets, hi-plane slots
#pragma unroll
  for (int m = 0; m < 4; ++m)
    aoffs[m] = (unsigned)((wr * 64 + m * 16 + lr) * 64 + ((lg ^ sw) * 8));
#pragma unroll
  for (int n = 0; n < 4; ++n)
    boffs[n] = (unsigned)((wc * 64 + n * 16 + lr) * 64 + ((lg ^ sw) * 8));

  for (int k0 = 0; k0 < K; k0 += 32) {
#pragma unroll
    for (int i = 0; i < 4; ++i) {
      gload_lds16(sp0[i], &U[0][(w * 32 + i * 8) * 64]);
      sp0[i] += 32;
      if constexpr (SPLIT) {
        gload_lds16(sp1[i], &U[1][(w * 32 + i * 8) * 64]);
        sp1[i] += 32;
      }
    }
    __syncthreads();  // drains vmcnt: LDS tiles ready
    f16x8 afh[4], bfh[4], afl[4], bfl[4];
    if constexpr (SPLIT) {
#pragma unroll
      for (int m = 0; m < 4; ++m) afh[m] = *(const f16x8*)&U[0][aoffs[m]];
#pragma unroll
      for (int m = 0; m < 4; ++m) afl[m] = *(const f16x8*)&U[0][aoffs[m] ^ 32];
#pragma unroll
      for (int n = 0; n < 4; ++n) bfh[n] = *(const f16x8*)&U[1][boffs[n]];
#pragma unroll
      for (int n = 0; n < 4; ++n) bfl[n] = *(const f16x8*)&U[1][boffs[n] ^ 32];
    } else {
#pragma unroll
      for (int m = 0; m < 4; ++m) afh[m] = *(const f16x8*)&U[0][aoffs[m]];
#pragma unroll
      for (int n = 0; n < 4; ++n) bfh[n] = *(const f16x8*)&U[0][boffs[n] ^ 32];
    }
#pragma unroll
    for (int m = 0; m < 4; ++m)
#pragma unroll
      for (int n = 0; n < 4; ++n) {
        acc[m][n] = __builtin_amdgcn_mfma_f32_16x16x32_f16(afh[m], bfh[n], acc[m][n], 0, 0, 0);
        if constexpr (SPLIT) {
          acc[m][n] = __builtin_amdgcn_mfma_f32_16x16x32_f16(afh[m], bfl[n], acc[m][n], 0, 0, 0);
          acc[m][n] = __builtin_amdgcn_mfma_f32_16x16x32_f16(afl[m], bfh[n], acc[m][n], 0, 0, 0);
        }
      }
    __syncthreads();  // all reads done before next stage overwrites
  }

  float bv[4];
#pragma unroll
  for (int n = 0; n < 4; ++n) bv[n] = biasq[bn + wc * 64 + n * 16 + lr];

#pragma unroll
  for (int m = 0; m < 4; ++m) {
#pragma unroll
    for (int j = 0; j < 4; ++j) {
      int rowg = bm + wr * 64 + m * 16 + lg * 4 + j;
      if (MODE != 0 && rowg >= rows) continue;
      size_t crow = (size_t)((MODE == 0) ? rowg : (r0 + rowg)) * N;
#pragma unroll
      for (int n = 0; n < 4; ++n) {
        float v = acc[m][n][j] + bv[n];
        if (RELU) v = fmaxf(v, 0.f);
        size_t o = crow + bn + wc * 64 + n * 16 + lr;
        if (OUTK == 0) {
          ((float*)out0)[o] = v;
        } else if (OUTK == 1) {
          ((unsigned short*)out0)[o] = f2h(v);
        } else {
          unsigned short hi, lo;
          fsplit(v, hi, lo);
          ((unsigned short*)out0)[o] = hi;
          ((unsigned short*)out1)[o] = lo;
        }
      }
    }
  }
}

// ---------------- attention: 16 q-rows per block (fp32 in, f16 hi/lo out) ----------------
__global__ __launch_bounds__(256) void k_attn(const float* __restrict__ qkv,
                                              unsigned short* __restrict__ ohi,
                                              unsigned short* __restrict__ olo) {
  const int qt = blockIdx.x;
  const int hh = blockIdx.y;
  const int bb = blockIdx.z;
  const int tid = threadIdx.x;
  __shared__ float qs[16][64];
  __shared__ float ps[16][256];
  const int t0 = bb * SEQ + qt * 16;
  for (int i = tid; i < 16 * 64; i += 256) {
    int qi = i >> 6, d = i & 63;
    qs[qi][d] = qkv[(size_t)(t0 + qi) * (3 * DIM) + hh * 64 + d];
  }
  __syncthreads();
  float s[16];
#pragma unroll
  for (int qi = 0; qi < 16; ++qi) s[qi] = 0.f;
  const float* krow = qkv + (size_t)(bb * SEQ + tid) * (3 * DIM) + DIM + hh * 64;
#pragma unroll 4
  for (int c = 0; c < 16; ++c) {
    float4 kv = *(const float4*)(krow + c * 4);
#pragma unroll
    for (int qi = 0; qi < 16; ++qi) {
      s[qi] += kv.x * qs[qi][c * 4 + 0] + kv.y * qs[qi][c * 4 + 1] +
               kv.z * qs[qi][c * 4 + 2] + kv.w * qs[qi][c * 4 + 3];
    }
  }
#pragma unroll
  for (int qi = 0; qi < 16; ++qi) ps[qi][tid] = s[qi] * 0.125f;
  __syncthreads();
  const int wv = tid >> 6, lane = tid & 63;
  for (int rr = wv; rr < 16; rr += 4) {
    float v[4];
#pragma unroll
    for (int j = 0; j < 4; ++j) v[j] = ps[rr][lane + 64 * j];
    float m = fmaxf(fmaxf(v[0], v[1]), fmaxf(v[2], v[3]));
    for (int msk = 32; msk; msk >>= 1) m = fmaxf(m, __shfl_xor(m, msk));
    float e[4], sum = 0.f;
#pragma unroll
    for (int j = 0; j < 4; ++j) { e[j] = expf(v[j] - m); sum += e[j]; }
    for (int msk = 32; msk; msk >>= 1) sum += __shfl_xor(sum, msk);
    float inv = 1.0f / sum;
#pragma unroll
    for (int j = 0; j < 4; ++j) ps[rr][lane + 64 * j] = e[j] * inv;
  }
  __syncthreads();
  const int qi0 = tid >> 6, d = tid & 63;
  float acc[4] = {0.f, 0.f, 0.f, 0.f};
  const float* vbase = qkv + (size_t)(bb * SEQ) * (3 * DIM) + 2 * DIM + hh * 64 + d;
  for (int k = 0; k < 256; ++k) {
    float vv = vbase[(size_t)k * (3 * DIM)];
    acc[0] += ps[qi0][k] * vv;
    acc[1] += ps[qi0 + 4][k] * vv;
    acc[2] += ps[qi0 + 8][k] * vv;
    acc[3] += ps[qi0 + 12][k] * vv;
  }
#pragma unroll
  for (int j = 0; j < 4; ++j) {
    size_t o = (size_t)(t0 + qi0 + 4 * j) * DIM + hh * 64 + d;
    fsplit(acc[j], ohi[o], olo[o]);
  }
}

// ---------------- block reduce helper ----------------
__device__ __forceinline__ float block_reduce_sum(float v, float* red) {
  const int tid = threadIdx.x;
  red[tid] = v;
  __syncthreads();
  for (int s = 128; s > 0; s >>= 1) {
    if (tid < s) red[tid] += red[tid + s];
    __syncthreads();
  }
  float r = red[0];
  __syncthreads();
  return r;
}

// ---------------- x = LN(xin + add), fp32 + f16 hi/lo out ----------------
__global__ __launch_bounds__(256) void k_add_ln(const float* __restrict__ xin,
                                                const float* __restrict__ add,
                                                const float* __restrict__ g,
                                                const float* __restrict__ bt,
                                                float* __restrict__ xout,
                                                unsigned short* __restrict__ xhi,
                                                unsigned short* __restrict__ xlo) {
  __shared__ float red[256];
  const int t = blockIdx.x, tid = threadIdx.x;
  const size_t base = (size_t)t * DIM;
  float v[4];
  float s = 0.f;
#pragma unroll
  for (int j = 0; j < 4; ++j) {
    int d = tid + 256 * j;
    v[j] = xin[base + d] + add[base + d];
    s += v[j];
  }
  float mean = block_reduce_sum(s, red) * (1.0f / DIM);
  float s2 = 0.f;
#pragma unroll
  for (int j = 0; j < 4; ++j) { float dv = v[j] - mean; s2 += dv * dv; }
  float var = block_reduce_sum(s2, red) * (1.0f / DIM);
  float rs = rsqrtf(var + 1e-5f);
#pragma unroll
  for (int j = 0; j < 4; ++j) {
    int d = tid + 256 * j;
    float o = (v[j] - mean) * rs * g[d] + bt[d];
    xout[base + d] = o;
    fsplit(o, xhi[base + d], xlo[base + d]);
  }
}

// ---------------- gate: logits (to d_out), top-2 + softmax weights ----------------
__global__ __launch_bounds__(256) void k_gate(const float* __restrict__ x,
                                              const float* __restrict__ gw,
                                              const float* __restrict__ gb,
                                              float* __restrict__ gout,
                                              int* __restrict__ topi,
                                              float* __restrict__ topw) {
  __shared__ float xs[DIM];
  __shared__ float lgs[NE];
  const int t = blockIdx.x, tid = threadIdx.x;
#pragma unroll
  for (int j = 0; j < 4; ++j) xs[tid + 256 * j] = x[(size_t)t * DIM + tid + 256 * j];
  __syncthreads();
  const int eg = tid >> 5, l32 = tid & 31;
  const float* wrow = gw + (size_t)eg * DIM;
  float p = 0.f;
  for (int j = 0; j < 32; ++j) {
    int d = l32 + 32 * j;
    p += xs[d] * wrow[d];
  }
  for (int m = 16; m; m >>= 1) p += __shfl_xor(p, m);
  if (l32 == 0) lgs[eg] = p;
  __syncthreads();
  if (tid < NE) {
    float v = lgs[tid] + gb[tid];
    gout[(size_t)t * NE + tid] = v;
    lgs[tid] = v;
  }
  __syncthreads();
  if (tid == 0) {
    int i0 = 0; float v0 = lgs[0];
    for (int i = 1; i < NE; ++i) if (lgs[i] > v0) { v0 = lgs[i]; i0 = i; }
    int i1 = -1; float v1 = -1e30f;
    for (int i = 0; i < NE; ++i) { if (i == i0) continue; if (lgs[i] > v1) { v1 = lgs[i]; i1 = i; } }
    float e1 = expf(v1 - v0);
    float w0 = 1.0f / (1.0f + e1);
    topi[2 * t] = i0; topi[2 * t + 1] = i1;
    topw[2 * t] = w0; topw[2 * t + 1] = e1 * w0;
  }
}

// ---------------- deterministic routing build ----------------
__global__ __launch_bounds__(512) void k_route(const int* __restrict__ topi,
                                               int* __restrict__ offg,
                                               int* __restrict__ slot_token,
                                               int* __restrict__ slot_of) {
  __shared__ int cnt_s[NE];
  __shared__ int off_s[NE + 1];
  const int tid = threadIdx.x;
  const int w = tid >> 6, lane = tid & 63;
  int c = 0;
  for (int i = lane; i < TKN * TOPK; i += 64) c += (topi[i] == w) ? 1 : 0;
  for (int m = 32; m; m >>= 1) c += __shfl_xor(c, m);
  if (lane == 0) cnt_s[w] = c;
  __syncthreads();
  if (tid == 0) {
    off_s[0] = 0;
    for (int e2 = 0; e2 < NE; ++e2) off_s[e2 + 1] = off_s[e2] + cnt_s[e2];
    for (int e2 = 0; e2 <= NE; ++e2) offg[e2] = off_s[e2];
  }
  __syncthreads();
  int base = off_s[w];
  for (int i0 = 0; i0 < TKN * TOPK; i0 += 64) {
    int i = i0 + lane;
    bool mm = (topi[i] == w);
    unsigned long long mask = __ballot(mm ? 1 : 0);
    int rank = __popcll(mask & ((1ull << lane) - 1ull));
    if (mm) {
      int slot = base + rank;
      slot_token[slot] = i >> 1;
      slot_of[i] = slot;
    }
    base += __popcll(mask);
  }
}

// ---------------- combine top-2 experts + residual + LN2 (fp32 + hi/lo out) ----------------
__global__ __launch_bounds__(256) void k_moe_combine_ln(const float* __restrict__ xin,
                                                        const float* __restrict__ y,
                                                        const float* __restrict__ topw,
                                                        const int* __restrict__ slot_of,
                                                        const float* __restrict__ g,
                                                        const float* __restrict__ bt,
                                                        float* __restrict__ xout,
                                                        unsigned short* __restrict__ xhi,
                                                        unsigned short* __restrict__ xlo) {
  __shared__ float red[256];
  const int t = blockIdx.x, tid = threadIdx.x;
  const float w0 = topw[2 * t], w1v = topw[2 * t + 1];
  const int s0 = slot_of[2 * t], s1 = slot_of[2 * t + 1];
  const size_t base = (size_t)t * DIM;
  float v[4];
  float s = 0.f;
#pragma unroll
  for (int j = 0; j < 4; ++j) {
    int d = tid + 256 * j;
    v[j] = xin[base + d] + w0 * y[(size_t)s0 * DIM + d] + w1v * y[(size_t)s1 * DIM + d];
    s += v[j];
  }
  float mean = block_reduce_sum(s, red) * (1.0f / DIM);
  float s2 = 0.f;
#pragma unroll
  for (int j = 0; j < 4; ++j) { float dv = v[j] - mean; s2 += dv * dv; }
  float var = block_reduce_sum(s2, red) * (1.0f / DIM);
  float rs = rsqrtf(var + 1e-5f);
#pragma unroll
  for (int j = 0; j < 4; ++j) {
    int d = tid + 256 * j;
    float o = (v[j] - mean) * rs * g[d] + bt[d];
    xout[base + d] = o;
    fsplit(o, xhi[base + d], xlo[base + d]);
  }
}

// ---------------- mean-pool over seq + classifier ----------------
__global__ __launch_bounds__(256) void k_pool_cls(const float* __restrict__ x,
                                                  const float* __restrict__ cw,
                                                  const float* __restrict__ cb,
                                                  float* __restrict__ out) {
  __shared__ float pooled[DIM];
  const int b = blockIdx.x, tid = threadIdx.x;
  float a[4] = {0.f, 0.f, 0.f, 0.f};
  for (int s = 0; s < SEQ; ++s) {
    const float* row = x + (size_t)(b * SEQ + s) * DIM;
#pragma unroll
    for (int j = 0; j < 4; ++j) a[j] += row[tid + 256 * j];
  }
#pragma unroll
  for (int j = 0; j < 4; ++j) pooled[tid + 256 * j] = a[j] * (1.0f / SEQ);
  __syncthreads();
  const int wv = tid >> 6, lane = tid & 63;
  for (int c = wv; c < NCLS; c += 4) {
    float p = 0.f;
    for (int d = lane; d < DIM; d += 64) p += pooled[d] * cw[(size_t)c * DIM + d];
    for (int m = 32; m; m >>= 1) p += __shfl_xor(p, m);
    if (lane == 0) out[b * NCLS + c] = p + cb[c];
  }
}

extern "C" void kernel_launch(void* const* d_in, const int* in_sizes, int n_in,
                              void* d_out, int out_size, void* d_ws, size_t ws_size,
                              hipStream_t stream) {
  const int*   src  = (const int*)  d_in[0];
  const float* emb  = (const float*)d_in[1];
  const float* ipw  = (const float*)d_in[2];
  const float* ipb  = (const float*)d_in[3];
  const float* ow   = (const float*)d_in[4];
  const float* ob   = (const float*)d_in[5];
  const float* ln1g = (const float*)d_in[6];
  const float* ln1b = (const float*)d_in[7];
  const float* ln2g = (const float*)d_in[8];
  const float* ln2b = (const float*)d_in[9];
  const float* gw   = (const float*)d_in[10];
  const float* gb   = (const float*)d_in[11];
  const float* w1   = (const float*)d_in[12];
  const float* b1   = (const float*)d_in[13];
  const float* w2   = (const float*)d_in[14];
  const float* b2   = (const float*)d_in[15];
  const float* cw   = (const float*)d_in[16];
  const float* cb   = (const float*)d_in[17];
  float* out = (float*)d_out;

  char* ws = (char*)d_ws;
  size_t off = 0;
  auto carve = [&](size_t bytes) -> void* {
    void* p = ws + off;
    off += (bytes + 255) & ~(size_t)255;
    return p;
  };
  float*          x     = (float*)carve((size_t)TKN * DIM * 4);
  unsigned short* xhi   = (unsigned short*)carve((size_t)TKN * DIM * 2);
  unsigned short* xlo   = (unsigned short*)carve((size_t)TKN * DIM * 2);
  // qkv fp32 (25.2MB) overlaps h hi+lo planes (2x16.8MB); qkv dead after attn
  char*           bufQ  = (char*)carve((size_t)2 * TKN * TOPK * HFF * 2);
  float*          qkv   = (float*)bufQ;
  unsigned short* h_hi  = (unsigned short*)bufQ;
  unsigned short* h_lo  = (unsigned short*)(bufQ + (size_t)TKN * TOPK * HFF * 2);
  unsigned short* at_hi = (unsigned short*)carve((size_t)TKN * DIM * 2);
  unsigned short* at_lo = (unsigned short*)carve((size_t)TKN * DIM * 2);
  // proj fp32 (8.4MB) overlaps ybuf fp32 (16.8MB); proj dead after add_ln
  char*           bufP  = (char*)carve((size_t)TKN * TOPK * DIM * 4);
  float*          proj  = (float*)bufP;
  float*          ybuf  = (float*)bufP;
  unsigned short* wq_hi = (unsigned short*)carve((size_t)3 * DIM * DIM * 2);
  unsigned short* wq_lo = (unsigned short*)carve((size_t)3 * DIM * DIM * 2);
  unsigned short* wo_hi = (unsigned short*)carve((size_t)DIM * DIM * 2);
  unsigned short* wo_lo = (unsigned short*)carve((size_t)DIM * DIM * 2);
  // w1t / w2t share (sequential use within a layer)
  unsigned short* wt_hi = (unsigned short*)carve((size_t)NE * DIM * HFF * 2);
  unsigned short* wt_lo = (unsigned short*)carve((size_t)NE * DIM * HFF * 2);
  float* topw       = (float*)carve((size_t)TKN * TOPK * 4);
  int*   topi       = (int*)  carve((size_t)TKN * TOPK * 4);
  int*   slot_token = (int*)  carve((size_t)TKN * TOPK * 4);
  int*   slot_of    = (int*)  carve((size_t)TKN * TOPK * 4);
  int*   offg       = (int*)  carve(64);

  k_embed<<<TKN, 256, 0, stream>>>(src, emb, x, xhi, xlo);

  for (int l = 0; l < NLAYER; ++l) {
    const float* ipw_l = ipw + (size_t)l * 3 * DIM * DIM;
    const float* ow_l  = ow  + (size_t)l * DIM * DIM;
    const float* w1_l  = w1  + (size_t)l * NE * DIM * HFF;
    const float* w2_l  = w2  + (size_t)l * NE * HFF * DIM;
    const bool sp = (l < NLAYER - 1);  // layer 3: single-pass (flips only touch pooled cls)

    k_cvt_split<<<(3 * DIM * DIM) / 1024, 256, 0, stream>>>(ipw_l, wq_hi, wq_lo);
    k_cvt_split<<<(DIM * DIM) / 1024, 256, 0, stream>>>(ow_l, wo_hi, wo_lo);
    k_cvt_t_split<<<dim3(HFF / 32, DIM / 32, NE), 256, 0, stream>>>(w1_l, wt_hi, wt_lo, DIM, HFF);

    // QKV: [2048,1024] x [3072,1024]^T -> qkv fp32
    if (sp)
      k_mfma_gemm<0, false, 0, true><<<dim3(3 * DIM / 128, TKN / 128), 256, 0, stream>>>(
          xhi, xlo, wq_hi, wq_lo, ipb + (size_t)l * 3 * DIM, qkv, nullptr, TKN, 3 * DIM, DIM, nullptr, nullptr);
    else
      k_mfma_gemm<0, false, 0, false><<<dim3(3 * DIM / 128, TKN / 128), 256, 0, stream>>>(
          xhi, xlo, wq_hi, wq_lo, ipb + (size_t)l * 3 * DIM, qkv, nullptr, TKN, 3 * DIM, DIM, nullptr, nullptr);

    k_attn<<<dim3(SEQ / 16, NHEAD, BATCH), 256, 0, stream>>>(qkv, at_hi, at_lo);

    // out-projection -> proj fp32
    if (sp)
      k_mfma_gemm<0, false, 0, true><<<dim3(DIM / 128, TKN / 128), 256, 0, stream>>>(
          at_hi, at_lo, wo_hi, wo_lo, ob + (size_t)l * DIM, proj, nullptr, TKN, DIM, DIM, nullptr, nullptr);
    else
      k_mfma_gemm<0, false, 0, false><<<dim3(DIM / 128, TKN / 128), 256, 0, stream>>>(
          at_hi, at_lo, wo_hi, wo_lo, ob + (size_t)l * DIM, proj, nullptr, TKN, DIM, DIM, nullptr, nullptr);

    k_add_ln<<<TKN, 256, 0, stream>>>(x, proj, ln1g + l * DIM, ln1b + l * DIM, x, xhi, xlo);

    k_gate<<<TKN, 256, 0, stream>>>(x, gw + (size_t)l * NE * DIM, gb + l * NE,
                                    out + NCLS * BATCH + (size_t)l * TKN * NE, topi, topw);
    k_route<<<1, 512, 0, stream>>>(topi, offg, slot_token, slot_of);

    // expert GEMM1 (gather): h = relu(x[tok] @ w1t^T + b1)
    if (sp)
      k_mfma_gemm<1, true, 2, true><<<dim3(HFF / 128, TKN * TOPK / 128, NE), 256, 0, stream>>>(
          xhi, xlo, wt_hi, wt_lo, b1 + (size_t)l * NE * HFF, h_hi, h_lo, 0, HFF, DIM, slot_token, offg);
    else
      k_mfma_gemm<1, true, 1, false><<<dim3(HFF / 128, TKN * TOPK / 128, NE), 256, 0, stream>>>(
          xhi, xlo, wt_hi, wt_lo, b1 + (size_t)l * NE * HFF, h_hi, nullptr, 0, HFF, DIM, slot_token, offg);

    // convert w2 (w1t dead after gemm1)
    k_cvt_t_split<<<dim3(DIM / 32, HFF / 32, NE), 256, 0, stream>>>(w2_l, wt_hi, wt_lo, HFF, DIM);

    // expert GEMM2: y = h @ w2t^T + b2, fp32 out
    if (sp)
      k_mfma_gemm<2, false, 0, true><<<dim3(DIM / 128, TKN * TOPK / 128, NE), 256, 0, stream>>>(
          h_hi, h_lo, wt_hi, wt_lo, b2 + (size_t)l * NE * DIM, ybuf, nullptr, 0, DIM, HFF, nullptr, offg);
    else
      k_mfma_gemm<2, false, 0, false><<<dim3(DIM / 128, TKN * TOPK / 128, NE), 256, 0, stream>>>(
          h_hi, h_lo, wt_hi, wt_lo, b2 + (size_t)l * NE * DIM, ybuf, nullptr, 0, DIM, HFF, nullptr, offg);

    k_moe_combine_ln<<<TKN, 256, 0, stream>>>(x, ybuf, topw, slot_of,
                                              ln2g + l * DIM, ln2b + l * DIM, x, xhi, xlo);
  }
  k_pool_cls<<<BATCH, 256, 0, stream>>>(x, cw, cb, out);
}

// Round 5
// 1568.428 us; speedup vs baseline: 2.5805x; 1.1098x over previous
//
#include <hip/hip_runtime.h>
#include <math.h>

#define TKN 2048
#define DIM 1024
#define NHEAD 16
#define HDIM 64
#define HFF 2048
#define NE 8
#define TOPK 2
#define NCLS 10
#define NLAYER 4
#define SEQ 256
#define BATCH 8

typedef __attribute__((ext_vector_type(8))) _Float16 f16x8;
typedef __attribute__((ext_vector_type(4))) float f32x4;

__device__ __forceinline__ unsigned short f2h(float v) {
  _Float16 h = (_Float16)v;
  return __builtin_bit_cast(unsigned short, h);
}
__device__ __forceinline__ float h2f(unsigned short u) {
  return (float)__builtin_bit_cast(_Float16, u);
}
__device__ __forceinline__ void fsplit(float v, unsigned short& hi, unsigned short& lo) {
  _Float16 h = (_Float16)v;
  hi = __builtin_bit_cast(unsigned short, h);
  lo = f2h(v - (float)h);
}

__device__ __forceinline__ void gload_lds16(const void* g, void* l) {
  __builtin_amdgcn_global_load_lds((__attribute__((address_space(1))) void*)g,
                                   (__attribute__((address_space(3))) void*)l,
                                   16, 0, 0);
}

// ---------------- embed + positional encoding (fp32 + f16 hi/lo out) ----------------
__global__ __launch_bounds__(256) void k_embed(const int* __restrict__ src,
                                               const float* __restrict__ emb,
                                               float* __restrict__ x,
                                               unsigned short* __restrict__ xhi,
                                               unsigned short* __restrict__ xlo) {
  const int t = blockIdx.x;
  const int tid = threadIdx.x;
  const int b = t / SEQ;
  const int tok = src[t];
  const float* erow = emb + (size_t)tok * DIM;
  const size_t base = (size_t)t * DIM;
  const float cexp = -9.210340371976184f / 1024.0f;  // -ln(10000)/D
#pragma unroll
  for (int j = 0; j < 4; ++j) {
    int d = tid + 256 * j;
    int i2 = d & ~1;
    float ang = (float)b * expf((float)i2 * cexp);
    float pe = (d & 1) ? cosf(ang) : sinf(ang);
    float v = erow[d] * 32.0f + pe;
    x[base + d] = v;
    fsplit(v, xhi[base + d], xlo[base + d]);
  }
}

// ---------------- fp32 -> f16 hi/lo planes ----------------
__global__ __launch_bounds__(256) void k_cvt_split(const float* __restrict__ in,
                                                   unsigned short* __restrict__ ohi,
                                                   unsigned short* __restrict__ olo) {
  int i = blockIdx.x * 256 + threadIdx.x;
  float4 v = ((const float4*)in)[i];
  ushort4 h, l;
  fsplit(v.x, h.x, l.x); fsplit(v.y, h.y, l.y);
  fsplit(v.z, h.z, l.z); fsplit(v.w, h.w, l.w);
  ((ushort4*)ohi)[i] = h;
  ((ushort4*)olo)[i] = l;
}

// ---------------- transpose + split: in [R][Cc] f32 -> out [Cc][R] f16 hi/lo ----------------
__global__ __launch_bounds__(256) void k_cvt_t_split(const float* __restrict__ in,
                                                     unsigned short* __restrict__ ohi,
                                                     unsigned short* __restrict__ olo,
                                                     int R, int Cc) {
  __shared__ float t[32][33];
  const int tx = threadIdx.x & 31, ty = threadIdx.x >> 5;  // 32 x 8
  const int c0 = blockIdx.x * 32, r0 = blockIdx.y * 32;
  const float* ip = in + (size_t)blockIdx.z * R * Cc;
  const size_t obase = (size_t)blockIdx.z * R * Cc;
#pragma unroll
  for (int j = 0; j < 4; ++j)
    t[ty + 8 * j][tx] = ip[(size_t)(r0 + ty + 8 * j) * Cc + c0 + tx];
  __syncthreads();
#pragma unroll
  for (int j = 0; j < 4; ++j) {
    unsigned short hi, lo;
    fsplit(t[tx][ty + 8 * j], hi, lo);
    size_t o = obase + (size_t)(c0 + ty + 8 * j) * R + r0 + tx;
    ohi[o] = hi;
    olo[o] = lo;
  }
}

// ---------------- compensated f16 MFMA GEMM: C[M,N] = A[M,K] * B[N,K]^T + bias ----------
// MODE 0: dense. MODE 1: MoE gather (A rows via slot_token). MODE 2: MoE contig.
// OUTK 0: fp32 out0. 1: f16-hi out0. 2: f16 hi out0 + lo out1.
// SPLIT: 3-pass compensated (hi*hi + hi*lo + lo*hi) vs single-pass hi*hi.
//
// T3-min schedule: double-buffered LDS; prefetch tile t+1 (global_load_lds) issued
// BEFORE computing tile t; ONE vmcnt(0)+s_barrier per K-step placed AFTER the MFMAs
// so the prefetch hides under ds_read+MFMA. LDS tiles [128 rows][8 slots x 16B],
// physical_slot = logical_slot ^ (row&7), realized by pre-swizzled global source.
template <int MODE, bool RELU, int OUTK, bool SPLIT>
__global__ __launch_bounds__(256) void k_mfma_gemm(
    const unsigned short* __restrict__ Ahi, const unsigned short* __restrict__ Alo,
    const unsigned short* __restrict__ Bhi, const unsigned short* __restrict__ Blo,
    const float* __restrict__ bias, void* __restrict__ out0, void* __restrict__ out1,
    int M, int N, int K,
    const int* __restrict__ slot_token, const int* __restrict__ offg) {
  constexpr int NP = SPLIT ? 2 : 1;
  __shared__ unsigned short U[2][NP][128 * 64];
  const int tid = threadIdx.x;
  const int w = tid >> 6, lane = tid & 63;
  const int bm = blockIdx.y * 128, bn = blockIdx.x * 128;
  int r0 = 0, rows = M, e = 0;
  if (MODE != 0) {
    e = blockIdx.z;
    r0 = offg[e];
    rows = offg[e + 1] - r0;
    if (bm >= rows) return;
  }
  const size_t bwb = (size_t)e * K * N;
  const float* biasq = bias + (size_t)e * N;

  // staging: lane covers (row = wave_base + i*8 + (lane>>3), physical slot lane&7)
  const int lrow8 = lane >> 3;
  const int s = (lane & 7) ^ lrow8;   // logical slot this lane must fetch
  const int chunk = (s & 3) * 8;      // k element offset of the 16B chunk
  const unsigned short* sp0[4];
  const unsigned short* sp1[4];
#pragma unroll
  for (int i = 0; i < 4; ++i) {
    int rloc = w * 32 + i * 8 + lrow8;  // tile row 0..127
    int growA;
    if (MODE == 0) {
      growA = bm + rloc;
    } else {
      int rr = bm + rloc;
      if (rr >= rows) rr = rows - 1;
      growA = (MODE == 1) ? slot_token[r0 + rr] : (r0 + rr);
    }
    size_t aoff = (size_t)growA * K + chunk;
    size_t boff = bwb + (size_t)(bn + rloc) * K + chunk;
    if constexpr (SPLIT) {
      sp0[i] = (s < 4 ? Ahi : Alo) + aoff;
      sp1[i] = (s < 4 ? Bhi : Blo) + boff;
    } else {
      sp0[i] = (s < 4) ? (Ahi + aoff) : (Bhi + boff);
      sp1[i] = nullptr;
    }
  }

  f32x4 acc[4][4] = {};
  const int wr = w >> 1, wc = w & 1;
  const int lr = lane & 15, lg = lane >> 4;
  const int sw = lr & 7;  // (row & 7) for this lane's fragment rows
  unsigned aoffs[4], boffs[4];  // ushort offsets, hi-plane slots
#pragma unroll
  for (int m = 0; m < 4; ++m)
    aoffs[m] = (unsigned)((wr * 64 + m * 16 + lr) * 64 + ((lg ^ sw) * 8));
#pragma unroll
  for (int n = 0; n < 4; ++n)
    boffs[n] = (unsigned)((wc * 64 + n * 16 + lr) * 64 + ((lg ^ sw) * 8));

  // ---- prologue: stage tile 0 into buffer 0, drain, barrier ----
#pragma unroll
  for (int i = 0; i < 4; ++i) {
    gload_lds16(sp0[i], &U[0][0][(w * 32 + i * 8) * 64]);
    sp0[i] += 32;
    if constexpr (SPLIT) {
      gload_lds16(sp1[i], &U[0][1][(w * 32 + i * 8) * 64]);
      sp1[i] += 32;
    }
  }
  asm volatile("s_waitcnt vmcnt(0)" ::: "memory");
  __builtin_amdgcn_s_barrier();

  const int NT = K / 32;
#pragma unroll 2
  for (int t = 0; t < NT; ++t) {
    const int cur = t & 1;
    // ---- issue prefetch of tile t+1 into the other buffer ----
    if (t + 1 < NT) {
#pragma unroll
      for (int i = 0; i < 4; ++i) {
        gload_lds16(sp0[i], &U[cur ^ 1][0][(w * 32 + i * 8) * 64]);
        sp0[i] += 32;
        if constexpr (SPLIT) {
          gload_lds16(sp1[i], &U[cur ^ 1][1][(w * 32 + i * 8) * 64]);
          sp1[i] += 32;
        }
      }
    }
    // ---- ds_read fragments from current buffer ----
    f16x8 afh[4], bfh[4], afl[4], bfl[4];
    if constexpr (SPLIT) {
#pragma unroll
      for (int m = 0; m < 4; ++m) afh[m] = *(const f16x8*)&U[cur][0][aoffs[m]];
#pragma unroll
      for (int m = 0; m < 4; ++m) afl[m] = *(const f16x8*)&U[cur][0][aoffs[m] ^ 32];
#pragma unroll
      for (int n = 0; n < 4; ++n) bfh[n] = *(const f16x8*)&U[cur][1][boffs[n]];
#pragma unroll
      for (int n = 0; n < 4; ++n) bfl[n] = *(const f16x8*)&U[cur][1][boffs[n] ^ 32];
    } else {
#pragma unroll
      for (int m = 0; m < 4; ++m) afh[m] = *(const f16x8*)&U[cur][0][aoffs[m]];
#pragma unroll
      for (int n = 0; n < 4; ++n) bfh[n] = *(const f16x8*)&U[cur][0][boffs[n] ^ 32];
    }
    // ---- MFMA (prefetch loads land underneath) ----
#pragma unroll
    for (int m = 0; m < 4; ++m)
#pragma unroll
      for (int n = 0; n < 4; ++n) {
        acc[m][n] = __builtin_amdgcn_mfma_f32_16x16x32_f16(afh[m], bfh[n], acc[m][n], 0, 0, 0);
        if constexpr (SPLIT) {
          acc[m][n] = __builtin_amdgcn_mfma_f32_16x16x32_f16(afh[m], bfl[n], acc[m][n], 0, 0, 0);
          acc[m][n] = __builtin_amdgcn_mfma_f32_16x16x32_f16(afl[m], bfh[n], acc[m][n], 0, 0, 0);
        }
      }
    // ---- single drain + barrier per K-step: next tile resident, readers done ----
    asm volatile("s_waitcnt vmcnt(0)" ::: "memory");
    __builtin_amdgcn_s_barrier();
  }

  float bv[4];
#pragma unroll
  for (int n = 0; n < 4; ++n) bv[n] = biasq[bn + wc * 64 + n * 16 + lr];

#pragma unroll
  for (int m = 0; m < 4; ++m) {
#pragma unroll
    for (int j = 0; j < 4; ++j) {
      int rowg = bm + wr * 64 + m * 16 + lg * 4 + j;
      if (MODE != 0 && rowg >= rows) continue;
      size_t crow = (size_t)((MODE == 0) ? rowg : (r0 + rowg)) * N;
#pragma unroll
      for (int n = 0; n < 4; ++n) {
        float v = acc[m][n][j] + bv[n];
        if (RELU) v = fmaxf(v, 0.f);
        size_t o = crow + bn + wc * 64 + n * 16 + lr;
        if (OUTK == 0) {
          ((float*)out0)[o] = v;
        } else if (OUTK == 1) {
          ((unsigned short*)out0)[o] = f2h(v);
        } else {
          unsigned short hi, lo;
          fsplit(v, hi, lo);
          ((unsigned short*)out0)[o] = hi;
          ((unsigned short*)out1)[o] = lo;
        }
      }
    }
  }
}

// ---------------- attention: 16 q-rows per block (fp32 in, f16 hi/lo out) ----------------
__global__ __launch_bounds__(256) void k_attn(const float* __restrict__ qkv,
                                              unsigned short* __restrict__ ohi,
                                              unsigned short* __restrict__ olo) {
  const int qt = blockIdx.x;
  const int hh = blockIdx.y;
  const int bb = blockIdx.z;
  const int tid = threadIdx.x;
  __shared__ float qs[16][64];
  __shared__ float ps[16][256];
  const int t0 = bb * SEQ + qt * 16;
  for (int i = tid; i < 16 * 64; i += 256) {
    int qi = i >> 6, d = i & 63;
    qs[qi][d] = qkv[(size_t)(t0 + qi) * (3 * DIM) + hh * 64 + d];
  }
  __syncthreads();
  float s[16];
#pragma unroll
  for (int qi = 0; qi < 16; ++qi) s[qi] = 0.f;
  const float* krow = qkv + (size_t)(bb * SEQ + tid) * (3 * DIM) + DIM + hh * 64;
#pragma unroll 4
  for (int c = 0; c < 16; ++c) {
    float4 kv = *(const float4*)(krow + c * 4);
#pragma unroll
    for (int qi = 0; qi < 16; ++qi) {
      s[qi] += kv.x * qs[qi][c * 4 + 0] + kv.y * qs[qi][c * 4 + 1] +
               kv.z * qs[qi][c * 4 + 2] + kv.w * qs[qi][c * 4 + 3];
    }
  }
#pragma unroll
  for (int qi = 0; qi < 16; ++qi) ps[qi][tid] = s[qi] * 0.125f;
  __syncthreads();
  const int wv = tid >> 6, lane = tid & 63;
  for (int rr = wv; rr < 16; rr += 4) {
    float v[4];
#pragma unroll
    for (int j = 0; j < 4; ++j) v[j] = ps[rr][lane + 64 * j];
    float m = fmaxf(fmaxf(v[0], v[1]), fmaxf(v[2], v[3]));
    for (int msk = 32; msk; msk >>= 1) m = fmaxf(m, __shfl_xor(m, msk));
    float e[4], sum = 0.f;
#pragma unroll
    for (int j = 0; j < 4; ++j) { e[j] = expf(v[j] - m); sum += e[j]; }
    for (int msk = 32; msk; msk >>= 1) sum += __shfl_xor(sum, msk);
    float inv = 1.0f / sum;
#pragma unroll
    for (int j = 0; j < 4; ++j) ps[rr][lane + 64 * j] = e[j] * inv;
  }
  __syncthreads();
  const int qi0 = tid >> 6, d = tid & 63;
  float acc[4] = {0.f, 0.f, 0.f, 0.f};
  const float* vbase = qkv + (size_t)(bb * SEQ) * (3 * DIM) + 2 * DIM + hh * 64 + d;
  for (int k = 0; k < 256; ++k) {
    float vv = vbase[(size_t)k * (3 * DIM)];
    acc[0] += ps[qi0][k] * vv;
    acc[1] += ps[qi0 + 4][k] * vv;
    acc[2] += ps[qi0 + 8][k] * vv;
    acc[3] += ps[qi0 + 12][k] * vv;
  }
#pragma unroll
  for (int j = 0; j < 4; ++j) {
    size_t o = (size_t)(t0 + qi0 + 4 * j) * DIM + hh * 64 + d;
    fsplit(acc[j], ohi[o], olo[o]);
  }
}

// ---------------- block reduce helper ----------------
__device__ __forceinline__ float block_reduce_sum(float v, float* red) {
  const int tid = threadIdx.x;
  red[tid] = v;
  __syncthreads();
  for (int s = 128; s > 0; s >>= 1) {
    if (tid < s) red[tid] += red[tid + s];
    __syncthreads();
  }
  float r = red[0];
  __syncthreads();
  return r;
}

// ---------------- x = LN(xin + add), fp32 + f16 hi/lo out ----------------
__global__ __launch_bounds__(256) void k_add_ln(const float* __restrict__ xin,
                                                const float* __restrict__ add,
                                                const float* __restrict__ g,
                                                const float* __restrict__ bt,
                                                float* __restrict__ xout,
                                                unsigned short* __restrict__ xhi,
                                                unsigned short* __restrict__ xlo) {
  __shared__ float red[256];
  const int t = blockIdx.x, tid = threadIdx.x;
  const size_t base = (size_t)t * DIM;
  float v[4];
  float s = 0.f;
#pragma unroll
  for (int j = 0; j < 4; ++j) {
    int d = tid + 256 * j;
    v[j] = xin[base + d] + add[base + d];
    s += v[j];
  }
  float mean = block_reduce_sum(s, red) * (1.0f / DIM);
  float s2 = 0.f;
#pragma unroll
  for (int j = 0; j < 4; ++j) { float dv = v[j] - mean; s2 += dv * dv; }
  float var = block_reduce_sum(s2, red) * (1.0f / DIM);
  float rs = rsqrtf(var + 1e-5f);
#pragma unroll
  for (int j = 0; j < 4; ++j) {
    int d = tid + 256 * j;
    float o = (v[j] - mean) * rs * g[d] + bt[d];
    xout[base + d] = o;
    fsplit(o, xhi[base + d], xlo[base + d]);
  }
}

// ---------------- gate: logits (to d_out), top-2 + softmax weights ----------------
__global__ __launch_bounds__(256) void k_gate(const float* __restrict__ x,
                                              const float* __restrict__ gw,
                                              const float* __restrict__ gb,
                                              float* __restrict__ gout,
                                              int* __restrict__ topi,
                                              float* __restrict__ topw) {
  __shared__ float xs[DIM];
  __shared__ float lgs[NE];
  const int t = blockIdx.x, tid = threadIdx.x;
#pragma unroll
  for (int j = 0; j < 4; ++j) xs[tid + 256 * j] = x[(size_t)t * DIM + tid + 256 * j];
  __syncthreads();
  const int eg = tid >> 5, l32 = tid & 31;
  const float* wrow = gw + (size_t)eg * DIM;
  float p = 0.f;
  for (int j = 0; j < 32; ++j) {
    int d = l32 + 32 * j;
    p += xs[d] * wrow[d];
  }
  for (int m = 16; m; m >>= 1) p += __shfl_xor(p, m);
  if (l32 == 0) lgs[eg] = p;
  __syncthreads();
  if (tid < NE) {
    float v = lgs[tid] + gb[tid];
    gout[(size_t)t * NE + tid] = v;
    lgs[tid] = v;
  }
  __syncthreads();
  if (tid == 0) {
    int i0 = 0; float v0 = lgs[0];
    for (int i = 1; i < NE; ++i) if (lgs[i] > v0) { v0 = lgs[i]; i0 = i; }
    int i1 = -1; float v1 = -1e30f;
    for (int i = 0; i < NE; ++i) { if (i == i0) continue; if (lgs[i] > v1) { v1 = lgs[i]; i1 = i; } }
    float e1 = expf(v1 - v0);
    float w0 = 1.0f / (1.0f + e1);
    topi[2 * t] = i0; topi[2 * t + 1] = i1;
    topw[2 * t] = w0; topw[2 * t + 1] = e1 * w0;
  }
}

// ---------------- deterministic routing build ----------------
__global__ __launch_bounds__(512) void k_route(const int* __restrict__ topi,
                                               int* __restrict__ offg,
                                               int* __restrict__ slot_token,
                                               int* __restrict__ slot_of) {
  __shared__ int cnt_s[NE];
  __shared__ int off_s[NE + 1];
  const int tid = threadIdx.x;
  const int w = tid >> 6, lane = tid & 63;
  int c = 0;
  for (int i = lane; i < TKN * TOPK; i += 64) c += (topi[i] == w) ? 1 : 0;
  for (int m = 32; m; m >>= 1) c += __shfl_xor(c, m);
  if (lane == 0) cnt_s[w] = c;
  __syncthreads();
  if (tid == 0) {
    off_s[0] = 0;
    for (int e2 = 0; e2 < NE; ++e2) off_s[e2 + 1] = off_s[e2] + cnt_s[e2];
    for (int e2 = 0; e2 <= NE; ++e2) offg[e2] = off_s[e2];
  }
  __syncthreads();
  int base = off_s[w];
  for (int i0 = 0; i0 < TKN * TOPK; i0 += 64) {
    int i = i0 + lane;
    bool mm = (topi[i] == w);
    unsigned long long mask = __ballot(mm ? 1 : 0);
    int rank = __popcll(mask & ((1ull << lane) - 1ull));
    if (mm) {
      int slot = base + rank;
      slot_token[slot] = i >> 1;
      slot_of[i] = slot;
    }
    base += __popcll(mask);
  }
}

// ---------------- combine top-2 experts + residual + LN2 (fp32 + hi/lo out) ----------------
__global__ __launch_bounds__(256) void k_moe_combine_ln(const float* __restrict__ xin,
                                                        const float* __restrict__ y,
                                                        const float* __restrict__ topw,
                                                        const int* __restrict__ slot_of,
                                                        const float* __restrict__ g,
                                                        const float* __restrict__ bt,
                                                        float* __restrict__ xout,
                                                        unsigned short* __restrict__ xhi,
                                                        unsigned short* __restrict__ xlo) {
  __shared__ float red[256];
  const int t = blockIdx.x, tid = threadIdx.x;
  const float w0 = topw[2 * t], w1v = topw[2 * t + 1];
  const int s0 = slot_of[2 * t], s1 = slot_of[2 * t + 1];
  const size_t base = (size_t)t * DIM;
  float v[4];
  float s = 0.f;
#pragma unroll
  for (int j = 0; j < 4; ++j) {
    int d = tid + 256 * j;
    v[j] = xin[base + d] + w0 * y[(size_t)s0 * DIM + d] + w1v * y[(size_t)s1 * DIM + d];
    s += v[j];
  }
  float mean = block_reduce_sum(s, red) * (1.0f / DIM);
  float s2 = 0.f;
#pragma unroll
  for (int j = 0; j < 4; ++j) { float dv = v[j] - mean; s2 += dv * dv; }
  float var = block_reduce_sum(s2, red) * (1.0f / DIM);
  float rs = rsqrtf(var + 1e-5f);
#pragma unroll
  for (int j = 0; j < 4; ++j) {
    int d = tid + 256 * j;
    float o = (v[j] - mean) * rs * g[d] + bt[d];
    xout[base + d] = o;
    fsplit(o, xhi[base + d], xlo[base + d]);
  }
}

// ---------------- mean-pool over seq + classifier ----------------
__global__ __launch_bounds__(256) void k_pool_cls(const float* __restrict__ x,
                                                  const float* __restrict__ cw,
                                                  const float* __restrict__ cb,
                                                  float* __restrict__ out) {
  __shared__ float pooled[DIM];
  const int b = blockIdx.x, tid = threadIdx.x;
  float a[4] = {0.f, 0.f, 0.f, 0.f};
  for (int s = 0; s < SEQ; ++s) {
    const float* row = x + (size_t)(b * SEQ + s) * DIM;
#pragma unroll
    for (int j = 0; j < 4; ++j) a[j] += row[tid + 256 * j];
  }
#pragma unroll
  for (int j = 0; j < 4; ++j) pooled[tid + 256 * j] = a[j] * (1.0f / SEQ);
  __syncthreads();
  const int wv = tid >> 6, lane = tid & 63;
  for (int c = wv; c < NCLS; c += 4) {
    float p = 0.f;
    for (int d = lane; d < DIM; d += 64) p += pooled[d] * cw[(size_t)c * DIM + d];
    for (int m = 32; m; m >>= 1) p += __shfl_xor(p, m);
    if (lane == 0) out[b * NCLS + c] = p + cb[c];
  }
}

extern "C" void kernel_launch(void* const* d_in, const int* in_sizes, int n_in,
                              void* d_out, int out_size, void* d_ws, size_t ws_size,
                              hipStream_t stream) {
  const int*   src  = (const int*)  d_in[0];
  const float* emb  = (const float*)d_in[1];
  const float* ipw  = (const float*)d_in[2];
  const float* ipb  = (const float*)d_in[3];
  const float* ow   = (const float*)d_in[4];
  const float* ob   = (const float*)d_in[5];
  const float* ln1g = (const float*)d_in[6];
  const float* ln1b = (const float*)d_in[7];
  const float* ln2g = (const float*)d_in[8];
  const float* ln2b = (const float*)d_in[9];
  const float* gw   = (const float*)d_in[10];
  const float* gb   = (const float*)d_in[11];
  const float* w1   = (const float*)d_in[12];
  const float* b1   = (const float*)d_in[13];
  const float* w2   = (const float*)d_in[14];
  const float* b2   = (const float*)d_in[15];
  const float* cw   = (const float*)d_in[16];
  const float* cb   = (const float*)d_in[17];
  float* out = (float*)d_out;

  char* ws = (char*)d_ws;
  size_t off = 0;
  auto carve = [&](size_t bytes) -> void* {
    void* p = ws + off;
    off += (bytes + 255) & ~(size_t)255;
    return p;
  };
  float*          x     = (float*)carve((size_t)TKN * DIM * 4);
  unsigned short* xhi   = (unsigned short*)carve((size_t)TKN * DIM * 2);
  unsigned short* xlo   = (unsigned short*)carve((size_t)TKN * DIM * 2);
  // qkv fp32 (25.2MB) overlaps h hi+lo planes (2x16.8MB); qkv dead after attn
  char*           bufQ  = (char*)carve((size_t)2 * TKN * TOPK * HFF * 2);
  float*          qkv   = (float*)bufQ;
  unsigned short* h_hi  = (unsigned short*)bufQ;
  unsigned short* h_lo  = (unsigned short*)(bufQ + (size_t)TKN * TOPK * HFF * 2);
  unsigned short* at_hi = (unsigned short*)carve((size_t)TKN * DIM * 2);
  unsigned short* at_lo = (unsigned short*)carve((size_t)TKN * DIM * 2);
  // proj fp32 (8.4MB) overlaps ybuf fp32 (16.8MB); proj dead after add_ln
  char*           bufP  = (char*)carve((size_t)TKN * TOPK * DIM * 4);
  float*          proj  = (float*)bufP;
  float*          ybuf  = (float*)bufP;
  unsigned short* wq_hi = (unsigned short*)carve((size_t)3 * DIM * DIM * 2);
  unsigned short* wq_lo = (unsigned short*)carve((size_t)3 * DIM * DIM * 2);
  unsigned short* wo_hi = (unsigned short*)carve((size_t)DIM * DIM * 2);
  unsigned short* wo_lo = (unsigned short*)carve((size_t)DIM * DIM * 2);
  // w1t / w2t share (sequential use within a layer)
  unsigned short* wt_hi = (unsigned short*)carve((size_t)NE * DIM * HFF * 2);
  unsigned short* wt_lo = (unsigned short*)carve((size_t)NE * DIM * HFF * 2);
  float* topw       = (float*)carve((size_t)TKN * TOPK * 4);
  int*   topi       = (int*)  carve((size_t)TKN * TOPK * 4);
  int*   slot_token = (int*)  carve((size_t)TKN * TOPK * 4);
  int*   slot_of    = (int*)  carve((size_t)TKN * TOPK * 4);
  int*   offg       = (int*)  carve(64);

  k_embed<<<TKN, 256, 0, stream>>>(src, emb, x, xhi, xlo);

  for (int l = 0; l < NLAYER; ++l) {
    const float* ipw_l = ipw + (size_t)l * 3 * DIM * DIM;
    const float* ow_l  = ow  + (size_t)l * DIM * DIM;
    const float* w1_l  = w1  + (size_t)l * NE * DIM * HFF;
    const float* w2_l  = w2  + (size_t)l * NE * HFF * DIM;
    const bool sp = (l < NLAYER - 1);  // layer 3: single-pass (flips only touch pooled cls)

    k_cvt_split<<<(3 * DIM * DIM) / 1024, 256, 0, stream>>>(ipw_l, wq_hi, wq_lo);
    k_cvt_split<<<(DIM * DIM) / 1024, 256, 0, stream>>>(ow_l, wo_hi, wo_lo);
    k_cvt_t_split<<<dim3(HFF / 32, DIM / 32, NE), 256, 0, stream>>>(w1_l, wt_hi, wt_lo, DIM, HFF);

    // QKV: [2048,1024] x [3072,1024]^T -> qkv fp32
    if (sp)
      k_mfma_gemm<0, false, 0, true><<<dim3(3 * DIM / 128, TKN / 128), 256, 0, stream>>>(
          xhi, xlo, wq_hi, wq_lo, ipb + (size_t)l * 3 * DIM, qkv, nullptr, TKN, 3 * DIM, DIM, nullptr, nullptr);
    else
      k_mfma_gemm<0, false, 0, false><<<dim3(3 * DIM / 128, TKN / 128), 256, 0, stream>>>(
          xhi, xlo, wq_hi, wq_lo, ipb + (size_t)l * 3 * DIM, qkv, nullptr, TKN, 3 * DIM, DIM, nullptr, nullptr);

    k_attn<<<dim3(SEQ / 16, NHEAD, BATCH), 256, 0, stream>>>(qkv, at_hi, at_lo);

    // out-projection -> proj fp32
    if (sp)
      k_mfma_gemm<0, false, 0, true><<<dim3(DIM / 128, TKN / 128), 256, 0, stream>>>(
          at_hi, at_lo, wo_hi, wo_lo, ob + (size_t)l * DIM, proj, nullptr, TKN, DIM, DIM, nullptr, nullptr);
    else
      k_mfma_gemm<0, false, 0, false><<<dim3(DIM / 128, TKN / 128), 256, 0, stream>>>(
          at_hi, at_lo, wo_hi, wo_lo, ob + (size_t)l * DIM, proj, nullptr, TKN, DIM, DIM, nullptr, nullptr);

    k_add_ln<<<TKN, 256, 0, stream>>>(x, proj, ln1g + l * DIM, ln1b + l * DIM, x, xhi, xlo);

    k_gate<<<TKN, 256, 0, stream>>>(x, gw + (size_t)l * NE * DIM, gb + l * NE,
                                    out + NCLS * BATCH + (size_t)l * TKN * NE, topi, topw);
    k_route<<<1, 512, 0, stream>>>(topi, offg, slot_token, slot_of);

    // expert GEMM1 (gather): h = relu(x[tok] @ w1t^T + b1)
    if (sp)
      k_mfma_gemm<1, true, 2, true><<<dim3(HFF / 128, TKN * TOPK / 128, NE), 256, 0, stream>>>(
          xhi, xlo, wt_hi, wt_lo, b1 + (size_t)l * NE * HFF, h_hi, h_lo, 0, HFF, DIM, slot_token, offg);
    else
      k_mfma_gemm<1, true, 1, false><<<dim3(HFF / 128, TKN * TOPK / 128, NE), 256, 0, stream>>>(
          xhi, xlo, wt_hi, wt_lo, b1 + (size_t)l * NE * HFF, h_hi, nullptr, 0, HFF, DIM, slot_token, offg);

    // convert w2 (w1t dead after gemm1)
    k_cvt_t_split<<<dim3(DIM / 32, HFF / 32, NE), 256, 0, stream>>>(w2_l, wt_hi, wt_lo, HFF, DIM);

    // expert GEMM2: y = h @ w2t^T + b2, fp32 out
    if (sp)
      k_mfma_gemm<2, false, 0, true><<<dim3(DIM / 128, TKN * TOPK / 128, NE), 256, 0, stream>>>(
          h_hi, h_lo, wt_hi, wt_lo, b2 + (size_t)l * NE * DIM, ybuf, nullptr, 0, DIM, HFF, nullptr, offg);
    else
      k_mfma_gemm<2, false, 0, false><<<dim3(DIM / 128, TKN * TOPK / 128, NE), 256, 0, stream>>>(
          h_hi, h_lo, wt_hi, wt_lo, b2 + (size_t)l * NE * DIM, ybuf, nullptr, 0, DIM, HFF, nullptr, offg);

    k_moe_combine_ln<<<TKN, 256, 0, stream>>>(x, ybuf, topw, slot_of,
                                              ln2g + l * DIM, ln2b + l * DIM, x, xhi, xlo);
  }
  k_pool_cls<<<BATCH, 256, 0, stream>>>(x, cw, cb, out);
}

// Round 6
// 1450.432 us; speedup vs baseline: 2.7904x; 1.0814x over previous
//
#include <hip/hip_runtime.h>
#include <math.h>

#define TKN 2048
#define DIM 1024
#define NHEAD 16
#define HDIM 64
#define HFF 2048
#define NE 8
#define TOPK 2
#define NCLS 10
#define NLAYER 4
#define SEQ 256
#define BATCH 8

typedef __attribute__((ext_vector_type(8))) _Float16 f16x8;
typedef __attribute__((ext_vector_type(4))) float f32x4;
typedef __attribute__((ext_vector_type(8))) unsigned short u16x8;

__device__ __forceinline__ unsigned short f2h(float v) {
  _Float16 h = (_Float16)v;
  return __builtin_bit_cast(unsigned short, h);
}
__device__ __forceinline__ float h2f(unsigned short u) {
  return (float)__builtin_bit_cast(_Float16, u);
}
__device__ __forceinline__ void fsplit(float v, unsigned short& hi, unsigned short& lo) {
  _Float16 h = (_Float16)v;
  hi = __builtin_bit_cast(unsigned short, h);
  lo = f2h(v - (float)h);
}

__device__ __forceinline__ void gload_lds16(const void* g, void* l) {
  __builtin_amdgcn_global_load_lds((__attribute__((address_space(1))) void*)g,
                                   (__attribute__((address_space(3))) void*)l,
                                   16, 0, 0);
}

// ---------------- embed + positional encoding (fp32 + f16 hi/lo out) ----------------
__global__ __launch_bounds__(256) void k_embed(const int* __restrict__ src,
                                               const float* __restrict__ emb,
                                               float* __restrict__ x,
                                               unsigned short* __restrict__ xhi,
                                               unsigned short* __restrict__ xlo) {
  const int t = blockIdx.x;
  const int tid = threadIdx.x;
  const int b = t / SEQ;
  const int tok = src[t];
  const float* erow = emb + (size_t)tok * DIM;
  const size_t base = (size_t)t * DIM;
  const float cexp = -9.210340371976184f / 1024.0f;  // -ln(10000)/D
#pragma unroll
  for (int j = 0; j < 4; ++j) {
    int d = tid + 256 * j;
    int i2 = d & ~1;
    float ang = (float)b * expf((float)i2 * cexp);
    float pe = (d & 1) ? cosf(ang) : sinf(ang);
    float v = erow[d] * 32.0f + pe;
    x[base + d] = v;
    fsplit(v, xhi[base + d], xlo[base + d]);
  }
}

// ---------------- fp32 -> f16 hi/lo planes ----------------
template <bool LO>
__global__ __launch_bounds__(256) void k_cvt_split(const float* __restrict__ in,
                                                   unsigned short* __restrict__ ohi,
                                                   unsigned short* __restrict__ olo) {
  int i = blockIdx.x * 256 + threadIdx.x;
  float4 v = ((const float4*)in)[i];
  ushort4 h, l;
  fsplit(v.x, h.x, l.x); fsplit(v.y, h.y, l.y);
  fsplit(v.z, h.z, l.z); fsplit(v.w, h.w, l.w);
  ((ushort4*)ohi)[i] = h;
  if (LO) ((ushort4*)olo)[i] = l;
}

// ---------------- transpose + split: in [R][Cc] f32 -> out [Cc][R] f16 hi(/lo) --------
// 64r x 32c tile; output as one ushort8 b128 store per thread (128B segments).
template <bool LO>
__global__ __launch_bounds__(256) void k_cvt_t2(const float* __restrict__ in,
                                                unsigned short* __restrict__ ohi,
                                                unsigned short* __restrict__ olo,
                                                int R, int Cc) {
  __shared__ float ts[64][33];
  const int t = threadIdx.x;
  const int c0 = blockIdx.x * 32, r0 = blockIdx.y * 64;
  const float* ip = in + (size_t)blockIdx.z * R * Cc;
  const size_t obase = (size_t)blockIdx.z * R * Cc;
  const int cc = t & 31, rr0 = t >> 5;  // 2 rows per wave pass, 8 passes
#pragma unroll
  for (int j = 0; j < 8; ++j)
    ts[rr0 + 8 * j][cc] = ip[(size_t)(r0 + rr0 + 8 * j) * Cc + c0 + cc];
  __syncthreads();
  const int c = t >> 3, rch = (t & 7) * 8;  // thread owns 8 consecutive r of col c
  u16x8 hv, lv;
#pragma unroll
  for (int i = 0; i < 8; ++i) {
    unsigned short hi, lo;
    fsplit(ts[rch + i][c], hi, lo);
    hv[i] = hi; lv[i] = lo;
  }
  size_t o = obase + (size_t)(c0 + c) * R + r0 + rch;
  *(u16x8*)(ohi + o) = hv;
  if (LO) *(u16x8*)(olo + o) = lv;
}

// ---------------- compensated f16 MFMA GEMM: C[M,N] = A[M,K] * B[N,K]^T + bias ----------
// MODE 0: dense. MODE 1: MoE gather (A rows via slot_token). MODE 2: MoE contig.
// OUTK 0: fp32 out0. 1: f16-hi out0. 2: f16 hi out0 + lo out1.
// SPLIT: 3-pass compensated (hi*hi + hi*lo + lo*hi) vs single-pass hi*hi.
// Double-buffered LDS; prefetch t+1 issued before compute of t; one vmcnt(0)+barrier
// per K-step after the MFMAs. [128 rows][8 slots x 16B], phys_slot = slot ^ (row&7).
template <int MODE, bool RELU, int OUTK, bool SPLIT>
__global__ __launch_bounds__(256) void k_mfma_gemm(
    const unsigned short* __restrict__ Ahi, const unsigned short* __restrict__ Alo,
    const unsigned short* __restrict__ Bhi, const unsigned short* __restrict__ Blo,
    const float* __restrict__ bias, void* __restrict__ out0, void* __restrict__ out1,
    int M, int N, int K,
    const int* __restrict__ slot_token, const int* __restrict__ offg) {
  constexpr int NP = SPLIT ? 2 : 1;
  __shared__ unsigned short U[2][NP][128 * 64];
  const int tid = threadIdx.x;
  const int w = tid >> 6, lane = tid & 63;
  const int bm = blockIdx.y * 128, bn = blockIdx.x * 128;
  int r0 = 0, rows = M, e = 0;
  if (MODE != 0) {
    e = blockIdx.z;
    r0 = offg[e];
    rows = offg[e + 1] - r0;
    if (bm >= rows) return;
  }
  const size_t bwb = (size_t)e * K * N;
  const float* biasq = bias + (size_t)e * N;

  // staging: lane covers (row = wave_base + i*8 + (lane>>3), physical slot lane&7)
  const int lrow8 = lane >> 3;
  const int s = (lane & 7) ^ lrow8;   // logical slot this lane must fetch
  const int chunk = (s & 3) * 8;      // k element offset of the 16B chunk
  const unsigned short* sp0[4];
  const unsigned short* sp1[4];
#pragma unroll
  for (int i = 0; i < 4; ++i) {
    int rloc = w * 32 + i * 8 + lrow8;  // tile row 0..127
    int growA;
    if (MODE == 0) {
      growA = bm + rloc;
    } else {
      int rr = bm + rloc;
      if (rr >= rows) rr = rows - 1;
      growA = (MODE == 1) ? slot_token[r0 + rr] : (r0 + rr);
    }
    size_t aoff = (size_t)growA * K + chunk;
    size_t boff = bwb + (size_t)(bn + rloc) * K + chunk;
    if constexpr (SPLIT) {
      sp0[i] = (s < 4 ? Ahi : Alo) + aoff;
      sp1[i] = (s < 4 ? Bhi : Blo) + boff;
    } else {
      sp0[i] = (s < 4) ? (Ahi + aoff) : (Bhi + boff);
      sp1[i] = nullptr;
    }
  }

  f32x4 acc[4][4] = {};
  const int wr = w >> 1, wc = w & 1;
  const int lr = lane & 15, lg = lane >> 4;
  const int sw = lr & 7;  // (row & 7) for this lane's fragment rows
  unsigned aoffs[4], boffs[4];  // ushort offsets, hi-plane slots
#pragma unroll
  for (int m = 0; m < 4; ++m)
    aoffs[m] = (unsigned)((wr * 64 + m * 16 + lr) * 64 + ((lg ^ sw) * 8));
#pragma unroll
  for (int n = 0; n < 4; ++n)
    boffs[n] = (unsigned)((wc * 64 + n * 16 + lr) * 64 + ((lg ^ sw) * 8));

  // ---- prologue: stage tile 0 into buffer 0, drain, barrier ----
#pragma unroll
  for (int i = 0; i < 4; ++i) {
    gload_lds16(sp0[i], &U[0][0][(w * 32 + i * 8) * 64]);
    sp0[i] += 32;
    if constexpr (SPLIT) {
      gload_lds16(sp1[i], &U[0][1][(w * 32 + i * 8) * 64]);
      sp1[i] += 32;
    }
  }
  asm volatile("s_waitcnt vmcnt(0)" ::: "memory");
  __builtin_amdgcn_s_barrier();

  const int NT = K / 32;
#pragma unroll 2
  for (int t = 0; t < NT; ++t) {
    const int cur = t & 1;
    // ---- issue prefetch of tile t+1 into the other buffer ----
    if (t + 1 < NT) {
#pragma unroll
      for (int i = 0; i < 4; ++i) {
        gload_lds16(sp0[i], &U[cur ^ 1][0][(w * 32 + i * 8) * 64]);
        sp0[i] += 32;
        if constexpr (SPLIT) {
          gload_lds16(sp1[i], &U[cur ^ 1][1][(w * 32 + i * 8) * 64]);
          sp1[i] += 32;
        }
      }
    }
    // ---- ds_read fragments from current buffer ----
    f16x8 afh[4], bfh[4], afl[4], bfl[4];
    if constexpr (SPLIT) {
#pragma unroll
      for (int m = 0; m < 4; ++m) afh[m] = *(const f16x8*)&U[cur][0][aoffs[m]];
#pragma unroll
      for (int m = 0; m < 4; ++m) afl[m] = *(const f16x8*)&U[cur][0][aoffs[m] ^ 32];
#pragma unroll
      for (int n = 0; n < 4; ++n) bfh[n] = *(const f16x8*)&U[cur][1][boffs[n]];
#pragma unroll
      for (int n = 0; n < 4; ++n) bfl[n] = *(const f16x8*)&U[cur][1][boffs[n] ^ 32];
    } else {
#pragma unroll
      for (int m = 0; m < 4; ++m) afh[m] = *(const f16x8*)&U[cur][0][aoffs[m]];
#pragma unroll
      for (int n = 0; n < 4; ++n) bfh[n] = *(const f16x8*)&U[cur][0][boffs[n] ^ 32];
    }
    // ---- MFMA (prefetch loads land underneath) ----
#pragma unroll
    for (int m = 0; m < 4; ++m)
#pragma unroll
      for (int n = 0; n < 4; ++n) {
        acc[m][n] = __builtin_amdgcn_mfma_f32_16x16x32_f16(afh[m], bfh[n], acc[m][n], 0, 0, 0);
        if constexpr (SPLIT) {
          acc[m][n] = __builtin_amdgcn_mfma_f32_16x16x32_f16(afh[m], bfl[n], acc[m][n], 0, 0, 0);
          acc[m][n] = __builtin_amdgcn_mfma_f32_16x16x32_f16(afl[m], bfh[n], acc[m][n], 0, 0, 0);
        }
      }
    // ---- single drain + barrier per K-step ----
    asm volatile("s_waitcnt vmcnt(0)" ::: "memory");
    __builtin_amdgcn_s_barrier();
  }

  float bv[4];
#pragma unroll
  for (int n = 0; n < 4; ++n) bv[n] = biasq[bn + wc * 64 + n * 16 + lr];

#pragma unroll
  for (int m = 0; m < 4; ++m) {
#pragma unroll
    for (int j = 0; j < 4; ++j) {
      int rowg = bm + wr * 64 + m * 16 + lg * 4 + j;
      if (MODE != 0 && rowg >= rows) continue;
      size_t crow = (size_t)((MODE == 0) ? rowg : (r0 + rowg)) * N;
#pragma unroll
      for (int n = 0; n < 4; ++n) {
        float v = acc[m][n][j] + bv[n];
        if (RELU) v = fmaxf(v, 0.f);
        size_t o = crow + bn + wc * 64 + n * 16 + lr;
        if (OUTK == 0) {
          ((float*)out0)[o] = v;
        } else if (OUTK == 1) {
          ((unsigned short*)out0)[o] = f2h(v);
        } else {
          unsigned short hi, lo;
          fsplit(v, hi, lo);
          ((unsigned short*)out0)[o] = hi;
          ((unsigned short*)out1)[o] = lo;
        }
      }
    }
  }
}

// ---------------- attention: 16 q-rows per block (fp32 in, f16 hi/lo out) ----------------
__global__ __launch_bounds__(256) void k_attn(const float* __restrict__ qkv,
                                              unsigned short* __restrict__ ohi,
                                              unsigned short* __restrict__ olo) {
  const int qt = blockIdx.x;
  const int hh = blockIdx.y;
  const int bb = blockIdx.z;
  const int tid = threadIdx.x;
  __shared__ float qs[16][64];
  __shared__ float ps[16][256];
  const int t0 = bb * SEQ + qt * 16;
  for (int i = tid; i < 16 * 64; i += 256) {
    int qi = i >> 6, d = i & 63;
    qs[qi][d] = qkv[(size_t)(t0 + qi) * (3 * DIM) + hh * 64 + d];
  }
  __syncthreads();
  float s[16];
#pragma unroll
  for (int qi = 0; qi < 16; ++qi) s[qi] = 0.f;
  const float* krow = qkv + (size_t)(bb * SEQ + tid) * (3 * DIM) + DIM + hh * 64;
#pragma unroll 4
  for (int c = 0; c < 16; ++c) {
    float4 kv = *(const float4*)(krow + c * 4);
#pragma unroll
    for (int qi = 0; qi < 16; ++qi) {
      s[qi] += kv.x * qs[qi][c * 4 + 0] + kv.y * qs[qi][c * 4 + 1] +
               kv.z * qs[qi][c * 4 + 2] + kv.w * qs[qi][c * 4 + 3];
    }
  }
#pragma unroll
  for (int qi = 0; qi < 16; ++qi) ps[qi][tid] = s[qi] * 0.125f;
  __syncthreads();
  const int wv = tid >> 6, lane = tid & 63;
  for (int rr = wv; rr < 16; rr += 4) {
    float v[4];
#pragma unroll
    for (int j = 0; j < 4; ++j) v[j] = ps[rr][lane + 64 * j];
    float m = fmaxf(fmaxf(v[0], v[1]), fmaxf(v[2], v[3]));
    for (int msk = 32; msk; msk >>= 1) m = fmaxf(m, __shfl_xor(m, msk));
    float e[4], sum = 0.f;
#pragma unroll
    for (int j = 0; j < 4; ++j) { e[j] = expf(v[j] - m); sum += e[j]; }
    for (int msk = 32; msk; msk >>= 1) sum += __shfl_xor(sum, msk);
    float inv = 1.0f / sum;
#pragma unroll
    for (int j = 0; j < 4; ++j) ps[rr][lane + 64 * j] = e[j] * inv;
  }
  __syncthreads();
  const int qi0 = tid >> 6, d = tid & 63;
  float acc[4] = {0.f, 0.f, 0.f, 0.f};
  const float* vbase = qkv + (size_t)(bb * SEQ) * (3 * DIM) + 2 * DIM + hh * 64 + d;
  for (int k = 0; k < 256; ++k) {
    float vv = vbase[(size_t)k * (3 * DIM)];
    acc[0] += ps[qi0][k] * vv;
    acc[1] += ps[qi0 + 4][k] * vv;
    acc[2] += ps[qi0 + 8][k] * vv;
    acc[3] += ps[qi0 + 12][k] * vv;
  }
#pragma unroll
  for (int j = 0; j < 4; ++j) {
    size_t o = (size_t)(t0 + qi0 + 4 * j) * DIM + hh * 64 + d;
    fsplit(acc[j], ohi[o], olo[o]);
  }
}

// ---------------- block reduce helper ----------------
__device__ __forceinline__ float block_reduce_sum(float v, float* red) {
  const int tid = threadIdx.x;
  red[tid] = v;
  __syncthreads();
  for (int s = 128; s > 0; s >>= 1) {
    if (tid < s) red[tid] += red[tid + s];
    __syncthreads();
  }
  float r = red[0];
  __syncthreads();
  return r;
}

// ---------------- x = LN(xin + add), fp32 + f16 hi/lo out ----------------
__global__ __launch_bounds__(256) void k_add_ln(const float* __restrict__ xin,
                                                const float* __restrict__ add,
                                                const float* __restrict__ g,
                                                const float* __restrict__ bt,
                                                float* __restrict__ xout,
                                                unsigned short* __restrict__ xhi,
                                                unsigned short* __restrict__ xlo) {
  __shared__ float red[256];
  const int t = blockIdx.x, tid = threadIdx.x;
  const size_t base = (size_t)t * DIM;
  float v[4];
  float s = 0.f;
#pragma unroll
  for (int j = 0; j < 4; ++j) {
    int d = tid + 256 * j;
    v[j] = xin[base + d] + add[base + d];
    s += v[j];
  }
  float mean = block_reduce_sum(s, red) * (1.0f / DIM);
  float s2 = 0.f;
#pragma unroll
  for (int j = 0; j < 4; ++j) { float dv = v[j] - mean; s2 += dv * dv; }
  float var = block_reduce_sum(s2, red) * (1.0f / DIM);
  float rs = rsqrtf(var + 1e-5f);
#pragma unroll
  for (int j = 0; j < 4; ++j) {
    int d = tid + 256 * j;
    float o = (v[j] - mean) * rs * g[d] + bt[d];
    xout[base + d] = o;
    fsplit(o, xhi[base + d], xlo[base + d]);
  }
}

// ---------------- gate: logits (to d_out), top-2 + softmax weights ----------------
__global__ __launch_bounds__(256) void k_gate(const float* __restrict__ x,
                                              const float* __restrict__ gw,
                                              const float* __restrict__ gb,
                                              float* __restrict__ gout,
                                              int* __restrict__ topi,
                                              float* __restrict__ topw) {
  __shared__ float xs[DIM];
  __shared__ float lgs[NE];
  const int t = blockIdx.x, tid = threadIdx.x;
#pragma unroll
  for (int j = 0; j < 4; ++j) xs[tid + 256 * j] = x[(size_t)t * DIM + tid + 256 * j];
  __syncthreads();
  const int eg = tid >> 5, l32 = tid & 31;
  const float* wrow = gw + (size_t)eg * DIM;
  float p = 0.f;
  for (int j = 0; j < 32; ++j) {
    int d = l32 + 32 * j;
    p += xs[d] * wrow[d];
  }
  for (int m = 16; m; m >>= 1) p += __shfl_xor(p, m);
  if (l32 == 0) lgs[eg] = p;
  __syncthreads();
  if (tid < NE) {
    float v = lgs[tid] + gb[tid];
    gout[(size_t)t * NE + tid] = v;
    lgs[tid] = v;
  }
  __syncthreads();
  if (tid == 0) {
    int i0 = 0; float v0 = lgs[0];
    for (int i = 1; i < NE; ++i) if (lgs[i] > v0) { v0 = lgs[i]; i0 = i; }
    int i1 = -1; float v1 = -1e30f;
    for (int i = 0; i < NE; ++i) { if (i == i0) continue; if (lgs[i] > v1) { v1 = lgs[i]; i1 = i; } }
    float e1 = expf(v1 - v0);
    float w0 = 1.0f / (1.0f + e1);
    topi[2 * t] = i0; topi[2 * t + 1] = i1;
    topw[2 * t] = w0; topw[2 * t + 1] = e1 * w0;
  }
}

// ---------------- deterministic routing build ----------------
__global__ __launch_bounds__(512) void k_route(const int* __restrict__ topi,
                                               int* __restrict__ offg,
                                               int* __restrict__ slot_token,
                                               int* __restrict__ slot_of) {
  __shared__ int cnt_s[NE];
  __shared__ int off_s[NE + 1];
  const int tid = threadIdx.x;
  const int w = tid >> 6, lane = tid & 63;
  int c = 0;
  for (int i = lane; i < TKN * TOPK; i += 64) c += (topi[i] == w) ? 1 : 0;
  for (int m = 32; m; m >>= 1) c += __shfl_xor(c, m);
  if (lane == 0) cnt_s[w] = c;
  __syncthreads();
  if (tid == 0) {
    off_s[0] = 0;
    for (int e2 = 0; e2 < NE; ++e2) off_s[e2 + 1] = off_s[e2] + cnt_s[e2];
    for (int e2 = 0; e2 <= NE; ++e2) offg[e2] = off_s[e2];
  }
  __syncthreads();
  int base = off_s[w];
  for (int i0 = 0; i0 < TKN * TOPK; i0 += 64) {
    int i = i0 + lane;
    bool mm = (topi[i] == w);
    unsigned long long mask = __ballot(mm ? 1 : 0);
    int rank = __popcll(mask & ((1ull << lane) - 1ull));
    if (mm) {
      int slot = base + rank;
      slot_token[slot] = i >> 1;
      slot_of[i] = slot;
    }
    base += __popcll(mask);
  }
}

// ---------------- combine top-2 experts + residual + LN2 (fp32 + hi/lo out) ----------------
__global__ __launch_bounds__(256) void k_moe_combine_ln(const float* __restrict__ xin,
                                                        const float* __restrict__ y,
                                                        const float* __restrict__ topw,
                                                        const int* __restrict__ slot_of,
                                                        const float* __restrict__ g,
                                                        const float* __restrict__ bt,
                                                        float* __restrict__ xout,
                                                        unsigned short* __restrict__ xhi,
                                                        unsigned short* __restrict__ xlo) {
  __shared__ float red[256];
  const int t = blockIdx.x, tid = threadIdx.x;
  const float w0 = topw[2 * t], w1v = topw[2 * t + 1];
  const int s0 = slot_of[2 * t], s1 = slot_of[2 * t + 1];
  const size_t base = (size_t)t * DIM;
  float v[4];
  float s = 0.f;
#pragma unroll
  for (int j = 0; j < 4; ++j) {
    int d = tid + 256 * j;
    v[j] = xin[base + d] + w0 * y[(size_t)s0 * DIM + d] + w1v * y[(size_t)s1 * DIM + d];
    s += v[j];
  }
  float mean = block_reduce_sum(s, red) * (1.0f / DIM);
  float s2 = 0.f;
#pragma unroll
  for (int j = 0; j < 4; ++j) { float dv = v[j] - mean; s2 += dv * dv; }
  float var = block_reduce_sum(s2, red) * (1.0f / DIM);
  float rs = rsqrtf(var + 1e-5f);
#pragma unroll
  for (int j = 0; j < 4; ++j) {
    int d = tid + 256 * j;
    float o = (v[j] - mean) * rs * g[d] + bt[d];
    xout[base + d] = o;
    fsplit(o, xhi[base + d], xlo[base + d]);
  }
}

// ---------------- mean-pool over seq + classifier ----------------
__global__ __launch_bounds__(256) void k_pool_cls(const float* __restrict__ x,
                                                  const float* __restrict__ cw,
                                                  const float* __restrict__ cb,
                                                  float* __restrict__ out) {
  __shared__ float pooled[DIM];
  const int b = blockIdx.x, tid = threadIdx.x;
  float a[4] = {0.f, 0.f, 0.f, 0.f};
  for (int s = 0; s < SEQ; ++s) {
    const float* row = x + (size_t)(b * SEQ + s) * DIM;
#pragma unroll
    for (int j = 0; j < 4; ++j) a[j] += row[tid + 256 * j];
  }
#pragma unroll
  for (int j = 0; j < 4; ++j) pooled[tid + 256 * j] = a[j] * (1.0f / SEQ);
  __syncthreads();
  const int wv = tid >> 6, lane = tid & 63;
  for (int c = wv; c < NCLS; c += 4) {
    float p = 0.f;
    for (int d = lane; d < DIM; d += 64) p += pooled[d] * cw[(size_t)c * DIM + d];
    for (int m = 32; m; m >>= 1) p += __shfl_xor(p, m);
    if (lane == 0) out[b * NCLS + c] = p + cb[c];
  }
}

extern "C" void kernel_launch(void* const* d_in, const int* in_sizes, int n_in,
                              void* d_out, int out_size, void* d_ws, size_t ws_size,
                              hipStream_t stream) {
  const int*   src  = (const int*)  d_in[0];
  const float* emb  = (const float*)d_in[1];
  const float* ipw  = (const float*)d_in[2];
  const float* ipb  = (const float*)d_in[3];
  const float* ow   = (const float*)d_in[4];
  const float* ob   = (const float*)d_in[5];
  const float* ln1g = (const float*)d_in[6];
  const float* ln1b = (const float*)d_in[7];
  const float* ln2g = (const float*)d_in[8];
  const float* ln2b = (const float*)d_in[9];
  const float* gw   = (const float*)d_in[10];
  const float* gb   = (const float*)d_in[11];
  const float* w1   = (const float*)d_in[12];
  const float* b1   = (const float*)d_in[13];
  const float* w2   = (const float*)d_in[14];
  const float* b2   = (const float*)d_in[15];
  const float* cw   = (const float*)d_in[16];
  const float* cb   = (const float*)d_in[17];
  float* out = (float*)d_out;

  char* ws = (char*)d_ws;
  size_t off = 0;
  auto carve = [&](size_t bytes) -> void* {
    void* p = ws + off;
    off += (bytes + 255) & ~(size_t)255;
    return p;
  };
  float*          x     = (float*)carve((size_t)TKN * DIM * 4);
  unsigned short* xhi   = (unsigned short*)carve((size_t)TKN * DIM * 2);
  unsigned short* xlo   = (unsigned short*)carve((size_t)TKN * DIM * 2);
  // qkv fp32 (25.2MB) overlaps h hi+lo planes (2x16.8MB); qkv dead after attn
  char*           bufQ  = (char*)carve((size_t)2 * TKN * TOPK * HFF * 2);
  float*          qkv   = (float*)bufQ;
  unsigned short* h_hi  = (unsigned short*)bufQ;
  unsigned short* h_lo  = (unsigned short*)(bufQ + (size_t)TKN * TOPK * HFF * 2);
  unsigned short* at_hi = (unsigned short*)carve((size_t)TKN * DIM * 2);
  unsigned short* at_lo = (unsigned short*)carve((size_t)TKN * DIM * 2);
  // proj fp32 (8.4MB) overlaps ybuf fp32 (16.8MB); proj dead after add_ln
  char*           bufP  = (char*)carve((size_t)TKN * TOPK * DIM * 4);
  float*          proj  = (float*)bufP;
  float*          ybuf  = (float*)bufP;
  unsigned short* wq_hi = (unsigned short*)carve((size_t)3 * DIM * DIM * 2);
  unsigned short* wq_lo = (unsigned short*)carve((size_t)3 * DIM * DIM * 2);
  unsigned short* wo_hi = (unsigned short*)carve((size_t)DIM * DIM * 2);
  unsigned short* wo_lo = (unsigned short*)carve((size_t)DIM * DIM * 2);
  // w1t / w2t share (sequential use within a layer)
  unsigned short* wt_hi = (unsigned short*)carve((size_t)NE * DIM * HFF * 2);
  unsigned short* wt_lo = (unsigned short*)carve((size_t)NE * DIM * HFF * 2);
  float* topw       = (float*)carve((size_t)TKN * TOPK * 4);
  int*   topi       = (int*)  carve((size_t)TKN * TOPK * 4);
  int*   slot_token = (int*)  carve((size_t)TKN * TOPK * 4);
  int*   slot_of    = (int*)  carve((size_t)TKN * TOPK * 4);
  int*   offg       = (int*)  carve(64);

  k_embed<<<TKN, 256, 0, stream>>>(src, emb, x, xhi, xlo);

  for (int l = 0; l < NLAYER; ++l) {
    const float* ipw_l = ipw + (size_t)l * 3 * DIM * DIM;
    const float* ow_l  = ow  + (size_t)l * DIM * DIM;
    const float* w1_l  = w1  + (size_t)l * NE * DIM * HFF;
    const float* w2_l  = w2  + (size_t)l * NE * HFF * DIM;
    // routing must be bit-exact for layers 0-2 -> dense path 3-pass through l=2.
    // layer-l MoE only affects gates AFTER l -> MoE 3-pass needed only for l<2.
    const bool spd = (l < 3);
    const bool spm = (l < 2);

    if (spd) {
      k_cvt_split<true><<<(3 * DIM * DIM) / 1024, 256, 0, stream>>>(ipw_l, wq_hi, wq_lo);
      k_cvt_split<true><<<(DIM * DIM) / 1024, 256, 0, stream>>>(ow_l, wo_hi, wo_lo);
    } else {
      k_cvt_split<false><<<(3 * DIM * DIM) / 1024, 256, 0, stream>>>(ipw_l, wq_hi, wq_lo);
      k_cvt_split<false><<<(DIM * DIM) / 1024, 256, 0, stream>>>(ow_l, wo_hi, wo_lo);
    }
    if (spm)
      k_cvt_t2<true><<<dim3(HFF / 32, DIM / 64, NE), 256, 0, stream>>>(w1_l, wt_hi, wt_lo, DIM, HFF);
    else
      k_cvt_t2<false><<<dim3(HFF / 32, DIM / 64, NE), 256, 0, stream>>>(w1_l, wt_hi, wt_lo, DIM, HFF);

    // QKV: [2048,1024] x [3072,1024]^T -> qkv fp32
    if (spd)
      k_mfma_gemm<0, false, 0, true><<<dim3(3 * DIM / 128, TKN / 128), 256, 0, stream>>>(
          xhi, xlo, wq_hi, wq_lo, ipb + (size_t)l * 3 * DIM, qkv, nullptr, TKN, 3 * DIM, DIM, nullptr, nullptr);
    else
      k_mfma_gemm<0, false, 0, false><<<dim3(3 * DIM / 128, TKN / 128), 256, 0, stream>>>(
          xhi, xlo, wq_hi, wq_lo, ipb + (size_t)l * 3 * DIM, qkv, nullptr, TKN, 3 * DIM, DIM, nullptr, nullptr);

    k_attn<<<dim3(SEQ / 16, NHEAD, BATCH), 256, 0, stream>>>(qkv, at_hi, at_lo);

    // out-projection -> proj fp32
    if (spd)
      k_mfma_gemm<0, false, 0, true><<<dim3(DIM / 128, TKN / 128), 256, 0, stream>>>(
          at_hi, at_lo, wo_hi, wo_lo, ob + (size_t)l * DIM, proj, nullptr, TKN, DIM, DIM, nullptr, nullptr);
    else
      k_mfma_gemm<0, false, 0, false><<<dim3(DIM / 128, TKN / 128), 256, 0, stream>>>(
          at_hi, at_lo, wo_hi, wo_lo, ob + (size_t)l * DIM, proj, nullptr, TKN, DIM, DIM, nullptr, nullptr);

    k_add_ln<<<TKN, 256, 0, stream>>>(x, proj, ln1g + l * DIM, ln1b + l * DIM, x, xhi, xlo);

    k_gate<<<TKN, 256, 0, stream>>>(x, gw + (size_t)l * NE * DIM, gb + l * NE,
                                    out + NCLS * BATCH + (size_t)l * TKN * NE, topi, topw);
    k_route<<<1, 512, 0, stream>>>(topi, offg, slot_token, slot_of);

    // expert GEMM1 (gather): h = relu(x[tok] @ w1t^T + b1)
    if (spm)
      k_mfma_gemm<1, true, 2, true><<<dim3(HFF / 128, TKN * TOPK / 128, NE), 256, 0, stream>>>(
          xhi, xlo, wt_hi, wt_lo, b1 + (size_t)l * NE * HFF, h_hi, h_lo, 0, HFF, DIM, slot_token, offg);
    else
      k_mfma_gemm<1, true, 1, false><<<dim3(HFF / 128, TKN * TOPK / 128, NE), 256, 0, stream>>>(
          xhi, xlo, wt_hi, wt_lo, b1 + (size_t)l * NE * HFF, h_hi, nullptr, 0, HFF, DIM, slot_token, offg);

    // convert w2 (w1t dead after gemm1)
    if (spm)
      k_cvt_t2<true><<<dim3(DIM / 32, HFF / 64, NE), 256, 0, stream>>>(w2_l, wt_hi, wt_lo, HFF, DIM);
    else
      k_cvt_t2<false><<<dim3(DIM / 32, HFF / 64, NE), 256, 0, stream>>>(w2_l, wt_hi, wt_lo, HFF, DIM);

    // expert GEMM2: y = h @ w2t^T + b2, fp32 out
    if (spm)
      k_mfma_gemm<2, false, 0, true><<<dim3(DIM / 128, TKN * TOPK / 128, NE), 256, 0, stream>>>(
          h_hi, h_lo, wt_hi, wt_lo, b2 + (size_t)l * NE * DIM, ybuf, nullptr, 0, DIM, HFF, nullptr, offg);
    else
      k_mfma_gemm<2, false, 0, false><<<dim3(DIM / 128, TKN * TOPK / 128, NE), 256, 0, stream>>>(
          h_hi, h_lo, wt_hi, wt_lo, b2 + (size_t)l * NE * DIM, ybuf, nullptr, 0, DIM, HFF, nullptr, offg);

    k_moe_combine_ln<<<TKN, 256, 0, stream>>>(x, ybuf, topw, slot_of,
                                              ln2g + l * DIM, ln2b + l * DIM, x, xhi, xlo);
  }
  k_pool_cls<<<BATCH, 256, 0, stream>>>(x, cw, cb, out);
}